// Round 6
// baseline (537.019 us; speedup 1.0000x reference)
//
#include <hip/hip_runtime.h>
#include <hip/hip_bf16.h>

typedef __hip_bfloat16 bf16;
typedef __attribute__((ext_vector_type(8))) short bf16x8;
typedef __attribute__((ext_vector_type(8))) unsigned short ushort8;
typedef __attribute__((ext_vector_type(4))) float f32x4;

#define BT 8
#define HH 64
#define WW 64
#define NSP (HH*WW)          // 4096 spatial per batch
#define DD 512
#define CF 128
#define IC 640
#define NG 64                // windows per batch
#define NM 64                // global tokens per batch
#define TRI 1536             // fused qkv row stride
#define EPS 1e-5f

static __device__ __forceinline__ float b2f(bf16 v) { return __bfloat162float(v); }
static __device__ __forceinline__ bf16 f2b(float v) { return __float2bfloat16(v); }
static __device__ __forceinline__ float u2f(unsigned short u) {
    return __uint_as_float((unsigned)u << 16);
}
static __device__ __forceinline__ unsigned short f2u(float v) {
    bf16 b = __float2bfloat16(v);
    return __builtin_bit_cast(unsigned short, b);
}

// ---------------- dtype detector ----------------
__global__ void detect_dtype(const void* __restrict__ x, int* __restrict__ flag) {
    __shared__ int cnt;
    if (threadIdx.x == 0) cnt = 0;
    __syncthreads();
    const unsigned* w = (const unsigned*)x;
    int local = 0;
    for (int i = threadIdx.x; i < 4096; i += 256) {
        float v = __uint_as_float(w[i]);
        float a = fabsf(v);
        if (a > 1e-5f && a < 1e4f) local++;
    }
    atomicAdd(&cnt, local);
    __syncthreads();
    if (threadIdx.x == 0) *flag = (cnt > 2048) ? 1 : 0;   // 1 = fp32, 0 = bf16
}

// ---------------- canonicalize weights to bf16 ----------------
#define NW 20
struct WTab {
    const void* src[NW];
    int pre[NW + 1];
};

__global__ void convert_weights(WTab t, const int* __restrict__ flag,
                                bf16* __restrict__ dst, int total) {
    int fp32 = *flag;
    for (int idx = blockIdx.x * blockDim.x + threadIdx.x; idx < total;
         idx += gridDim.x * blockDim.x) {
        int seg = 0;
        #pragma unroll
        for (int i = 0; i < NW; ++i) if (idx >= t.pre[i + 1]) seg = i + 1;
        int local = idx - t.pre[seg];
        bf16 v;
        if (fp32) v = f2b(((const float*)t.src[seg])[local]);
        else      v = ((const bf16*)t.src[seg])[local];
        dst[idx] = v;
    }
}

// ------- transpose 7 weights: [R][C] -> [C][R] (with dst stride) ----------------
#define NSEG 7
struct TT {
    int srcoff[NSEG], dstoff[NSEG], R[NSEG], C[NSEG], dstride[NSEG], tpre[NSEG + 1];
};
__global__ void transpose_weights(const bf16* __restrict__ wc, bf16* __restrict__ wt, TT t) {
    __shared__ unsigned short tile[32][33];
    int tb = blockIdx.x;
    int seg = 0;
    while (tb >= t.tpre[seg + 1]) seg++;
    int lt = tb - t.tpre[seg];
    int C = t.C[seg];
    int tpr = C / 32;
    int r0 = (lt / tpr) * 32, c0 = (lt % tpr) * 32;
    int ds = t.dstride[seg];
    const unsigned short* src = (const unsigned short*)(wc + t.srcoff[seg]);
    unsigned short* dst = (unsigned short*)(wt + t.dstoff[seg]);
    int tx = threadIdx.x & 31, ty = threadIdx.x >> 5;  // 32 x 8
    #pragma unroll
    for (int i = 0; i < 4; ++i)
        tile[ty + i * 8][tx] = src[(long long)(r0 + ty + i * 8) * C + c0 + tx];
    __syncthreads();
    #pragma unroll
    for (int i = 0; i < 4; ++i)
        dst[(long long)(c0 + ty + i * 8) * ds + r0 + tx] = tile[tx][ty + i * 8];
}

// ------- fold LN gamma/beta into transposed weight (in place, zero-pad K tail) ---
__global__ void fold_ln_weights(bf16* __restrict__ WT, int stride,
                                const bf16* __restrict__ g,
                                const bf16* __restrict__ b, const bf16* __restrict__ bias,
                                float* __restrict__ colsum, float* __restrict__ bias2,
                                int K, int Kpad) {
    int n = blockIdx.x;
    bf16* wrow = WT + (long long)n * stride;
    float s1 = 0.f, s2 = 0.f;
    for (int k = threadIdx.x; k < K; k += 256) {
        float w = b2f(wrow[k]);
        float gk = b2f(g[k]);
        wrow[k] = f2b(w * gk);
        s1 += w * gk;
        s2 += w * b2f(b[k]);
    }
    for (int k = K + threadIdx.x; k < Kpad; k += 256) wrow[k] = f2b(0.f);
    __shared__ float r1[256], r2[256];
    r1[threadIdx.x] = s1; r2[threadIdx.x] = s2;
    __syncthreads();
    for (int off = 128; off > 0; off >>= 1) {
        if (threadIdx.x < off) {
            r1[threadIdx.x] += r1[threadIdx.x + off];
            r2[threadIdx.x] += r2[threadIdx.x + off];
        }
        __syncthreads();
    }
    if (threadIdx.x == 0) {
        colsum[n] = r1[0];
        bias2[n]  = b2f(bias[n]) + r2[0];
    }
}

// ---------------- assemble qk = [x | f], vectorized, dual dtype ----------------
__global__ void assemble_qk_v(const void* __restrict__ xv, const void* __restrict__ fv,
                              const int* __restrict__ flag, bf16* __restrict__ qk,
                              int rows, long long xoff, long long foff) {
    int fp32 = *flag;
    long long total = (long long)rows * 80;        // 80 groups of 8 per row
    for (long long i = (long long)blockIdx.x * blockDim.x + threadIdx.x; i < total;
         i += (long long)gridDim.x * blockDim.x) {
        int row = (int)(i / 80);
        int g = (int)(i % 80);
        ushort8 o;
        if (g < 64) {
            long long s = xoff + (long long)row * DD + g * 8;
            if (fp32) {
                const float* xp = (const float*)xv + s;
                #pragma unroll
                for (int e = 0; e < 8; ++e) o[e] = f2u(xp[e]);
            } else {
                o = *(const ushort8*)((const unsigned short*)xv + s);
            }
        } else {
            long long s = foff + (long long)row * CF + (g - 64) * 8;
            if (fp32) {
                const float* fp = (const float*)fv + s;
                #pragma unroll
                for (int e = 0; e < 8; ++e) o[e] = f2u(fp[e]);
            } else {
                o = *(const ushort8*)((const unsigned short*)fv + s);
            }
        }
        *(ushort8*)((unsigned short*)qk + (long long)row * IC + g * 8) = o;
    }
}

// ------- vectorized depthwise convs (weights pre-transposed to [p][c]) ----------
__global__ __launch_bounds__(256)
void dwconv_fast(const bf16* __restrict__ qk,
                 const bf16* __restrict__ wkT, const bf16* __restrict__ bk_,
                 const bf16* __restrict__ wvT, const bf16* __restrict__ bv_,
                 bf16* __restrict__ kg, bf16* __restrict__ vg) {
    int bid = blockIdx.x;
    int chunk = bid % 10;
    int bm = bid / 10;
    int b = bm >> 6, m = bm & 63;
    int my = m >> 3, mx = m & 7;
    int tid = threadIdx.x;
    int c8 = tid & 7;
    int pg = tid >> 3;            // 0..31
    int cbase = chunk * 64 + c8 * 8;
    const unsigned short* sb = (const unsigned short*)qk + (long long)b * NSP * IC;
    const unsigned short* wku = (const unsigned short*)wkT;
    const unsigned short* wvu = (const unsigned short*)wvT;
    bool doV = chunk < 8;
    float ak[8] = {0,0,0,0,0,0,0,0}, av[8] = {0,0,0,0,0,0,0,0};
    #pragma unroll
    for (int pp = 0; pp < 2; ++pp) {
        int p = pg + pp * 32;
        int ky = p >> 3, kx = p & 7;
        int pos = (my * 8 + ky) * WW + mx * 8 + kx;
        ushort8 q = *(const ushort8*)&sb[(long long)pos * IC + cbase];
        ushort8 wk8 = *(const ushort8*)&wku[p * IC + cbase];
        #pragma unroll
        for (int e = 0; e < 8; ++e) ak[e] += u2f(q[e]) * u2f(wk8[e]);
        if (doV) {
            ushort8 wv8 = *(const ushort8*)&wvu[p * DD + cbase];
            #pragma unroll
            for (int e = 0; e < 8; ++e) av[e] += u2f(q[e]) * u2f(wv8[e]);
        }
    }
    #pragma unroll
    for (int off = 8; off <= 32; off <<= 1) {
        #pragma unroll
        for (int e = 0; e < 8; ++e) {
            ak[e] += __shfl_xor(ak[e], off, 64);
            av[e] += __shfl_xor(av[e], off, 64);
        }
    }
    __shared__ float lds[2][4][8][8];
    int wave = tid >> 6, lane = tid & 63;
    if (lane < 8) {
        #pragma unroll
        for (int e = 0; e < 8; ++e) {
            lds[0][wave][lane][e] = ak[e];
            lds[1][wave][lane][e] = av[e];
        }
    }
    __syncthreads();
    if (tid < 64) {
        int cc8 = tid >> 3, e = tid & 7;
        int c = chunk * 64 + cc8 * 8 + e;
        float k4 = lds[0][0][cc8][e] + lds[0][1][cc8][e]
                 + lds[0][2][cc8][e] + lds[0][3][cc8][e];
        kg[(long long)bm * IC + c] = f2b(k4 + b2f(bk_[c]));
        if (doV) {
            float v4 = lds[1][0][cc8][e] + lds[1][1][cc8][e]
                     + lds[1][2][cc8][e] + lds[1][3][cc8][e];
            vg[(long long)bm * IC + c] = f2b(v4 + b2f(bv_[c]));
        } else {
            vg[(long long)bm * IC + c] = f2b(0.f);
        }
    }
}

// ---------------- fused LN stats over qk: [0,512) and [0,640) in one pass -------
__global__ void stats_fused(const bf16* __restrict__ qk, float* __restrict__ stats_full,
                            float* __restrict__ stats_x, int rows) {
    int gt = blockIdx.x * blockDim.x + threadIdx.x;
    int wid = gt >> 6;
    int lane = gt & 63;
    if (wid >= rows) return;
    const unsigned short* p = (const unsigned short*)qk + (long long)wid * IC;
    ushort8 v = *(const ushort8*)(p + lane * 8);
    float s1 = 0.f, ss1 = 0.f, s2 = 0.f, ss2 = 0.f;
    #pragma unroll
    for (int e = 0; e < 8; ++e) { float f = u2f(v[e]); s1 += f; ss1 += f * f; }
    if (lane < 16) {
        ushort8 v2 = *(const ushort8*)(p + DD + lane * 8);
        #pragma unroll
        for (int e = 0; e < 8; ++e) { float f = u2f(v2[e]); s2 += f; ss2 += f * f; }
    }
    #pragma unroll
    for (int off = 32; off > 0; off >>= 1) {
        s1  += __shfl_down(s1,  off, 64);
        ss1 += __shfl_down(ss1, off, 64);
        s2  += __shfl_down(s2,  off, 64);
        ss2 += __shfl_down(ss2, off, 64);
    }
    if (lane == 0) {
        float m1 = s1 / 512.f;
        float var1 = ss1 / 512.f - m1 * m1;
        stats_x[wid * 2]     = m1;
        stats_x[wid * 2 + 1] = rsqrtf(var1 + EPS);
        float st = s1 + s2, sst = ss1 + ss2;
        float m2 = st / 640.f;
        float var2 = sst / 640.f - m2 * m2;
        stats_full[wid * 2]     = m2;
        stats_full[wid * 2 + 1] = rsqrtf(var2 + EPS);
    }
}

// ---------------- LN stats (generic, for glob rows) ----------------
__global__ void stats_kernel(const bf16* __restrict__ X, int lda, float* __restrict__ stats,
                             int rows, int K) {
    int gt = blockIdx.x * blockDim.x + threadIdx.x;
    int wid = gt >> 6;
    int lane = gt & 63;
    if (wid >= rows) return;
    const bf16* p = X + (long long)wid * lda;
    float s = 0.f, ss = 0.f;
    for (int k = lane; k < K; k += 64) {
        float v = b2f(p[k]);
        s += v; ss += v * v;
    }
    #pragma unroll
    for (int off = 32; off > 0; off >>= 1) {
        s  += __shfl_down(s,  off, 64);
        ss += __shfl_down(ss, off, 64);
    }
    if (lane == 0) {
        float m = s / K;
        float var = ss / K - m * m;
        stats[wid * 2]     = m;
        stats[wid * 2 + 1] = rsqrtf(var + EPS);
    }
}

// ---- MFMA GEMM template: BM x 128 tile, BM*2 threads (BM/32 waves) -------------
// BM=128: 4 waves (2Mx2N quadrants). BM=256: 8 waves (4Mx2N). Single-buffer m97 loop.
// Bmat TRANSPOSED: [N][K] row-major. M%BM==0, N%128==0, K%32==0.
// mode 0: C = acc + bias
// mode 2: C = rstd*(acc - mean*colsum) + bias2; row stats = statsQK if col<nQK else statsX
// mode 3: qk[row][DD+col] *= sigmoid(acc + bias)  (flow+reweight fused; C = qk)
// outflag (main region, mode 0): write Cout fp32/bf16 per *outflag at outoff.
// Glob tails (A2k != null, mode 2): extra y-blocks; col [512,1024) -> A2k/stats2k/C2k,
// col [1024,1536) -> A2v/stats2v/C2v; col<512 idle. A2/stats2 padded to BM rows.
template<int BM>
__global__ __launch_bounds__(BM * 2)
void gemm_mfma(const bf16* __restrict__ A, int lda,
               const float* __restrict__ statsQK, const float* __restrict__ statsX,
               int nQK,
               const float* __restrict__ colsum, const float* __restrict__ bias2,
               const bf16* __restrict__ Bmat,
               const bf16* __restrict__ bias,
               bf16* __restrict__ C,
               void* __restrict__ Cout, const int* __restrict__ outflag, long long outoff,
               const bf16* __restrict__ A2k, const float* __restrict__ stats2k,
               bf16* __restrict__ C2k,
               const bf16* __restrict__ A2v, const float* __restrict__ stats2v,
               bf16* __restrict__ C2v, int M2,
               int M, int N, int K, int mode) {
    __shared__ unsigned short As[BM * 32];    // [m][k] linear, 64B rows
    __shared__ unsigned short Bs[128 * 32];   // [n][k] linear
    int tid = threadIdx.x;

    // general bijective XCD-chunked swizzle (m204)
    int nwgx = gridDim.x;
    int nwg = nwgx * gridDim.y;
    int orig = blockIdx.y * nwgx + blockIdx.x;
    int qq = nwg >> 3, rr = nwg & 7;
    int xcd = orig & 7, idx = orig >> 3;
    int wg = (xcd < rr ? xcd * (qq + 1) : rr * (qq + 1) + (xcd - rr) * qq) + idx;
    int gy = wg / nwgx;
    int gx = wg % nwgx;
    int bn = gx * 128;

    int nby_main = M / BM;
    const bf16* Ap;
    const float* stp = nullptr;
    bf16* C2 = nullptr;
    int rowbase, mlim, glob, colOff = 0;
    if (gy < nby_main) {
        Ap = A; rowbase = gy * BM; mlim = M; glob = 0;
        if (mode == 2) stp = (bn >= nQK) ? statsX : statsQK;
    } else {
        if (bn < 512) return;                 // no Q projection for glob rows
        int isV = bn >= 1024;
        Ap = isV ? A2v : A2k;
        stp = isV ? stats2v : stats2k;
        C2 = isV ? C2v : C2k;
        colOff = isV ? 1024 : 512;
        rowbase = (gy - nby_main) * BM; mlim = M2; glob = 1;
    }

    int wave = tid >> 6, lane = tid & 63;
    int qm = (wave >> 1) * 64;    // BM=128: 0/64; BM=256: 0..192
    int qn = (wave & 1) * 64;
    int lm = lane & 15;
    int kq = (lane >> 4) * 8;
    int sr = lane >> 2;        // 0..15: row within 16-row stage segment
    int sc = (lane & 3) * 8;   // 16B chunk within 32-elem row

    f32x4 acc[4][4];
    #pragma unroll
    for (int i = 0; i < 4; ++i)
        #pragma unroll
        for (int j = 0; j < 4; ++j)
            acc[i][j] = (f32x4){0.f, 0.f, 0.f, 0.f};

    const unsigned short* Au = (const unsigned short*)Ap;
    const unsigned short* Bu = (const unsigned short*)Bmat;

    for (int k0 = 0; k0 < K; k0 += 32) {
        // stage A: BM/16 segments of (16 rows x 32 cols); each wave does 2.
        #pragma unroll
        for (int i = 0; i < 2; ++i) {
            int seg = wave * 2 + i;
            const unsigned short* gp =
                Au + (long long)(rowbase + seg * 16 + sr) * lda + k0 + sc;
            __builtin_amdgcn_global_load_lds(
                (const __attribute__((address_space(1))) void*)gp,
                (__attribute__((address_space(3))) void*)&As[seg * 512], 16, 0, 0);
        }
        // stage B: 8 segments; BM=128 -> 2/wave, BM=256 -> 1/wave.
        if constexpr (BM == 128) {
            #pragma unroll
            for (int i = 0; i < 2; ++i) {
                int seg = wave * 2 + i;
                const unsigned short* gp =
                    Bu + (long long)(bn + seg * 16 + sr) * K + k0 + sc;
                __builtin_amdgcn_global_load_lds(
                    (const __attribute__((address_space(1))) void*)gp,
                    (__attribute__((address_space(3))) void*)&Bs[seg * 512], 16, 0, 0);
            }
        } else {
            int seg = wave;
            const unsigned short* gp =
                Bu + (long long)(bn + seg * 16 + sr) * K + k0 + sc;
            __builtin_amdgcn_global_load_lds(
                (const __attribute__((address_space(1))) void*)gp,
                (__attribute__((address_space(3))) void*)&Bs[seg * 512], 16, 0, 0);
        }
        __syncthreads();
        bf16x8 af[4], bfr[4];
        #pragma unroll
        for (int i = 0; i < 4; ++i)
            af[i] = *(const bf16x8*)&As[(qm + i * 16 + lm) * 32 + kq];
        #pragma unroll
        for (int j = 0; j < 4; ++j)
            bfr[j] = *(const bf16x8*)&Bs[(qn + j * 16 + lm) * 32 + kq];
        #pragma unroll
        for (int i = 0; i < 4; ++i)
            #pragma unroll
            for (int j = 0; j < 4; ++j)
                acc[i][j] = __builtin_amdgcn_mfma_f32_16x16x32_bf16(
                    af[i], bfr[j], acc[i][j], 0, 0, 0);
        __syncthreads();
    }

    // ---- epilogue: C/D layout col=lane&15, row=(lane>>4)*4+reg ----
    int rq = (lane >> 4) * 4;
    float cs[4], bb[4];
    #pragma unroll
    for (int j = 0; j < 4; ++j) {
        int col = bn + qn + j * 16 + lm;
        if (mode == 2) { cs[j] = colsum[col]; bb[j] = bias2[col]; }
        else bb[j] = bias ? b2f(bias[col]) : 0.f;
    }
    int ofp = (!glob && outflag) ? *outflag : 0;
    #pragma unroll
    for (int i = 0; i < 4; ++i) {
        #pragma unroll
        for (int r = 0; r < 4; ++r) {
            int row = rowbase + qm + i * 16 + rq + r;
            if (row >= mlim) continue;
            float mean = 0.f, rstd = 0.f;
            if (mode == 2) { mean = stp[row * 2]; rstd = stp[row * 2 + 1]; }
            #pragma unroll
            for (int j = 0; j < 4; ++j) {
                int col = bn + qn + j * 16 + lm;
                float v = acc[i][j][r];
                if (mode == 2) v = rstd * (v - mean * cs[j]) + bb[j];
                else {
                    v += bb[j];
                    if (mode == 3) v = 1.f / (1.f + __expf(-v));
                }
                if (mode == 3) {
                    unsigned short* qp =
                        (unsigned short*)C + (long long)row * IC + DD + col;
                    *qp = f2u(u2f(*qp) * v);
                    continue;
                }
                if (glob) {
                    C2[(long long)row * 512 + (col - colOff)] = f2b(v);
                } else if (outflag) {
                    long long ci = (long long)row * N + col;
                    if (ofp) ((float*)Cout)[outoff + ci] = v;
                    else     ((bf16*)Cout)[outoff + ci] = f2b(v);
                } else {
                    C[(long long)row * N + col] = f2b(v);
                }
            }
        }
    }
}

// ---------------- MFMA attention (qkv fused input, stride TRI) ----------------
#define QS_STRIDE 72
#define PS_STRIDE 136
__global__ __launch_bounds__(256)
void attn_kernel(const bf16* __restrict__ qkv,
                 const bf16* __restrict__ key_glob, const bf16* __restrict__ val_glob,
                 bf16* __restrict__ attout) {
    int h = blockIdx.x & 7;
    int g = (blockIdx.x >> 3) & 63;
    int b = blockIdx.x >> 9;
    int gy = g >> 3, gx = g & 7;

    __shared__ unsigned short smem[64 * PS_STRIDE + 64 * PS_STRIDE];
    unsigned short* Qs = smem;                       // [64][QS_STRIDE]
    unsigned short* Ks = smem + 64 * QS_STRIDE;      // [128][QS_STRIDE]
    unsigned short* Ps = smem;                       // [64][PS_STRIDE]
    unsigned short* Vs = smem + 64 * PS_STRIDE;      // [64][PS_STRIDE] (d-major: [d][t])

    int tid = threadIdx.x;
    const unsigned short* QKV = (const unsigned short*)qkv;
    const unsigned short* KG = (const unsigned short*)key_glob;
    const unsigned short* VG = (const unsigned short*)val_glob;

    #pragma unroll
    for (int it = 0; it < 2; ++it) {
        int i = tid + it * 256;        // 512 units
        int t = i >> 3, dg = (i & 7) * 8;
        int ty = t >> 3, tx = t & 7;
        long long row = (long long)b * NSP + (gy * 8 + ty) * WW + gx * 8 + tx;
        *(ushort8*)&Qs[t * QS_STRIDE + dg] =
            *(const ushort8*)&QKV[row * TRI + h * 64 + dg];
    }
    #pragma unroll
    for (int it = 0; it < 4; ++it) {
        int i = tid + it * 256;        // 1024 units
        int t = i >> 3, dg = (i & 7) * 8;
        ushort8 kv;
        if (t < 64) {
            int ty = t >> 3, tx = t & 7;
            long long row = (long long)b * NSP + (gy * 8 + ty) * WW + gx * 8 + tx;
            kv = *(const ushort8*)&QKV[row * TRI + 512 + h * 64 + dg];
        } else {
            long long srow = (long long)b * NM + (t - 64);
            kv = *(const ushort8*)&KG[srow * DD + h * 64 + dg];
        }
        *(ushort8*)&Ks[t * QS_STRIDE + dg] = kv;
    }
    __syncthreads();

    int wave = tid >> 6, lane = tid & 63;
    int m0 = wave * 16;
    int lm = lane & 15;
    int quad = lane >> 4;            // 0..3

    f32x4 sacc[8];
    #pragma unroll
    for (int j = 0; j < 8; ++j) sacc[j] = (f32x4){0.f, 0.f, 0.f, 0.f};
    #pragma unroll
    for (int ks = 0; ks < 2; ++ks) {
        int kq = quad * 8 + ks * 32;
        bf16x8 af = *(const bf16x8*)&Qs[(m0 + lm) * QS_STRIDE + kq];
        #pragma unroll
        for (int j = 0; j < 8; ++j) {
            bf16x8 bfr = *(const bf16x8*)&Ks[(j * 16 + lm) * QS_STRIDE + kq];
            sacc[j] = __builtin_amdgcn_mfma_f32_16x16x32_bf16(af, bfr, sacc[j], 0, 0, 0);
        }
    }
    float pinv[4];
    #pragma unroll
    for (int r = 0; r < 4; ++r) {
        float mx = -1e30f;
        #pragma unroll
        for (int j = 0; j < 8; ++j) {
            sacc[j][r] *= 0.125f;
            mx = fmaxf(mx, sacc[j][r]);
        }
        mx = fmaxf(mx, __shfl_xor(mx, 1, 64));
        mx = fmaxf(mx, __shfl_xor(mx, 2, 64));
        mx = fmaxf(mx, __shfl_xor(mx, 4, 64));
        mx = fmaxf(mx, __shfl_xor(mx, 8, 64));
        float l = 0.f;
        #pragma unroll
        for (int j = 0; j < 8; ++j) {
            float p = __expf(sacc[j][r] - mx);
            sacc[j][r] = p;
            l += p;
        }
        l += __shfl_xor(l, 1, 64);
        l += __shfl_xor(l, 2, 64);
        l += __shfl_xor(l, 4, 64);
        l += __shfl_xor(l, 8, 64);
        pinv[r] = 1.f / l;
    }
    __syncthreads();   // all waves done reading Qs/Ks

    #pragma unroll
    for (int r = 0; r < 4; ++r) {
        int qrow = m0 + quad * 4 + r;
        #pragma unroll
        for (int j = 0; j < 8; ++j)
            Ps[qrow * PS_STRIDE + j * 16 + lm] = f2u(sacc[j][r] * pinv[r]);
    }
    #pragma unroll
    for (int it = 0; it < 4; ++it) {
        int i = tid + it * 256;        // 1024 units: t=128, dg=8
        int t = i & 127, dg = (i >> 7) * 8;
        ushort8 v;
        if (t < 64) {
            int ty = t >> 3, tx = t & 7;
            long long row = (long long)b * NSP + (gy * 8 + ty) * WW + gx * 8 + tx;
            v = *(const ushort8*)&QKV[row * TRI + 1024 + h * 64 + dg];
        } else {
            long long srow = (long long)b * NM + (t - 64);
            v = *(const ushort8*)&VG[srow * DD + h * 64 + dg];
        }
        #pragma unroll
        for (int e = 0; e < 8; ++e) Vs[(dg + e) * PS_STRIDE + t] = v[e];
    }
    __syncthreads();

    f32x4 oacc[4];
    #pragma unroll
    for (int j = 0; j < 4; ++j) oacc[j] = (f32x4){0.f, 0.f, 0.f, 0.f};
    #pragma unroll
    for (int ks = 0; ks < 4; ++ks) {
        int kq = quad * 8 + ks * 32;
        bf16x8 af = *(const bf16x8*)&Ps[(m0 + lm) * PS_STRIDE + kq];
        #pragma unroll
        for (int j = 0; j < 4; ++j) {
            bf16x8 bfr = *(const bf16x8*)&Vs[(j * 16 + lm) * PS_STRIDE + kq];
            oacc[j] = __builtin_amdgcn_mfma_f32_16x16x32_bf16(af, bfr, oacc[j], 0, 0, 0);
        }
    }
    #pragma unroll
    for (int r = 0; r < 4; ++r) {
        int qrow = m0 + quad * 4 + r;
        int ty = qrow >> 3, tx = qrow & 7;
        long long orow = (long long)b * NSP + (gy * 8 + ty) * WW + gx * 8 + tx;
        unsigned short* op = (unsigned short*)attout + orow * DD + h * 64;
        #pragma unroll
        for (int j = 0; j < 4; ++j)
            op[j * 16 + lm] = f2u(oacc[j][r]);
    }
}

static inline size_t alg(size_t b) { return (b + 255) & ~(size_t)255; }

extern "C" void kernel_launch(void* const* d_in, const int* in_sizes, int n_in,
                              void* d_out, int out_size, void* d_ws, size_t ws_size,
                              hipStream_t stream) {
    int s = (n_in > 2 && in_sizes[2] == 1) ? 0 : -1;

    const void* xv = d_in[0];
    const void* fv = d_in[1];
    const void* wsrc[NW];
    for (int i = 0; i < NW; ++i) wsrc[i] = d_in[3 + s + i];
    (void)out_size;

    const int wcnt[NW] = {327680, 512, 327680, 512, 262144, 512, 262144, 512,
                          40960, 640, 32768, 512, 640, 640, 640, 640, 512, 512,
                          81920, 128};
    WTab tab;
    int pre = 0;
    for (int i = 0; i < NW; ++i) {
        tab.src[i] = wsrc[i];
        tab.pre[i] = pre;
        pre += wcnt[i];
    }
    tab.pre[NW] = pre;
    const int wtotal = pre;

    char* ws = (char*)d_ws;
    size_t head = 0;
    int* flag = (int*)(ws + head); head += 256;
    bf16* wc = (bf16*)(ws + head); head += alg((size_t)wtotal * 2);
    // transposed weights: qkvW [1536][640] | WoT [512][512] | rwT [128][640]
    //                     | wkT [64][640] | wvT [64][512]
    const int off_qkvW = 0;
    const int off_WoT  = TRI * IC;                 // 983040
    const int off_rwT  = off_WoT + DD * DD;        // 1245184
    const int off_wkT  = off_rwT + CF * IC;        // 1327104
    const int off_wvT  = off_wkT + 64 * IC;        // 1368064
    const int wtpre    = off_wvT + 64 * DD;        // 1400832
    bf16* wt = (bf16*)(ws + head); head += alg((size_t)wtpre * 2);
    float* foldv = (float*)(ws + head); head += alg(2 * TRI * sizeof(float));
    float* cs_qkv = foldv;
    float* b2_qkv = foldv + TRI;

    const bf16* bq     = wc + tab.pre[1];
    const bf16* bk     = wc + tab.pre[3];
    const bf16* bv     = wc + tab.pre[5];
    const bf16* bo     = wc + tab.pre[7];
    const bf16* convKb = wc + tab.pre[9];
    const bf16* convVb = wc + tab.pre[11];
    const bf16* qn_g   = wc + tab.pre[12];
    const bf16* qn_b   = wc + tab.pre[13];
    const bf16* kn_g   = wc + tab.pre[14];
    const bf16* kn_b   = wc + tab.pre[15];
    const bf16* vn_g   = wc + tab.pre[16];
    const bf16* vn_b   = wc + tab.pre[17];
    const bf16* rw_b   = wc + tab.pre[19];
    bf16* qkvW = wt + off_qkvW;
    bf16* WoT  = wt + off_WoT;
    bf16* rwT  = wt + off_rwT;
    bf16* wkT  = wt + off_wkT;
    bf16* wvT  = wt + off_wvT;

    size_t avail = ws_size > head ? ws_size - head : 0;
    auto need = [&](int bc) -> size_t {
        size_t rows = (size_t)bc * NSP;
        size_t gm = (size_t)bc * NM, gmp = gm + 256;
        return alg(rows * IC * 2) + alg(rows * TRI * 2)
             + 2 * alg(gmp * IC * 2) + 2 * alg(gm * DD * 2)
             + 2 * alg(rows * 8) + 2 * alg(gmp * 8);
    };
    int nb = BT;
    while (nb > 1 && need(nb) > avail) nb--;

    detect_dtype<<<1, 256, 0, stream>>>(xv, flag);
    convert_weights<<<(wtotal + 255) / 256, 256, 0, stream>>>(tab, flag, wc, wtotal);
    {
        TT tt;
        const int srcsel[NSEG] = {0, 2, 4, 6, 18, 8, 10};
        const int Rr[NSEG]     = {IC, IC, DD, DD, IC, IC, DD};
        const int Cc[NSEG]     = {DD, DD, DD, DD, CF, 64, 64};
        const int dof[NSEG]    = {0, DD * IC, 2 * DD * IC, off_WoT, off_rwT,
                                  off_wkT, off_wvT};
        const int dstr[NSEG]   = {IC, IC, IC, DD, IC, IC, DD};
        int tp = 0;
        for (int i = 0; i < NSEG; ++i) {
            tt.srcoff[i] = tab.pre[srcsel[i]];
            tt.dstoff[i] = dof[i];
            tt.R[i] = Rr[i];
            tt.C[i] = Cc[i];
            tt.dstride[i] = dstr[i];
            tt.tpre[i] = tp;
            tp += (Rr[i] / 32) * (Cc[i] / 32);
        }
        tt.tpre[NSEG] = tp;
        transpose_weights<<<tp, 256, 0, stream>>>(wc, wt, tt);
    }
    // fold LN into qkvW rows; V region zero-padded in K to 640
    fold_ln_weights<<<DD, 256, 0, stream>>>(qkvW,              IC, qn_g, qn_b, bq,
                                            cs_qkv,       b2_qkv,       IC, IC);
    fold_ln_weights<<<DD, 256, 0, stream>>>(qkvW + DD * IC,    IC, kn_g, kn_b, bk,
                                            cs_qkv + 512, b2_qkv + 512, IC, IC);
    fold_ln_weights<<<DD, 256, 0, stream>>>(qkvW + 2 * DD * IC, IC, vn_g, vn_b, bv,
                                            cs_qkv + 1024, b2_qkv + 1024, DD, IC);

    for (int b0 = 0; b0 < BT; b0 += nb) {
        int bc = BT - b0 < nb ? BT - b0 : nb;
        int rows = bc * NSP;
        int gm = bc * NM;           // glob rows this chunk
        int gyg = (gm + 255) / 256; // extra y-blocks for glob tail (BM=256)

        size_t off = head;
        auto alloc = [&](size_t bytes) -> void* {
            void* p = ws + off; off += alg(bytes); return p;
        };
        size_t gmp = (size_t)gm + 256;  // padded for OOB staging reads (BM=256)
        bf16* qk        = (bf16*)alloc((size_t)rows * IC * 2);
        bf16* qkv       = (bf16*)alloc((size_t)rows * TRI * 2);
        bf16* kg        = (bf16*)alloc(gmp * IC * 2);
        bf16* vg        = (bf16*)alloc(gmp * IC * 2);   // stride IC, cols 512.. zeroed
        bf16* key_glob  = (bf16*)alloc((size_t)gm * DD * 2);
        bf16* val_glob  = (bf16*)alloc((size_t)gm * DD * 2);
        float* stats_qk = (float*)alloc((size_t)rows * 8);
        float* stats_x  = (float*)alloc((size_t)rows * 8);
        float* stats_kg = (float*)alloc(gmp * 8);
        float* stats_vg = (float*)alloc(gmp * 8);
        bf16* attout    = qk;        // alias: qk dead after fused QKV GEMM

        // 1. assemble qk = [x | f]
        {
            long long total = (long long)rows * 80;
            int blocks = (int)((total + 255) / 256);
            assemble_qk_v<<<blocks, 256, 0, stream>>>(
                xv, fv, flag, qk, rows,
                (long long)b0 * NSP * DD, (long long)b0 * NSP * CF);
        }
        // 2. flow gemm + reweight fused (mode 3): qk.f *= sigmoid(qk @ rw_W + rw_b)
        gemm_mfma<128><<<dim3(CF / 128, rows / 128), 256, 0, stream>>>(
            qk, IC, nullptr, nullptr, 0, nullptr, nullptr, rwT, rw_b, qk,
            nullptr, nullptr, 0,
            nullptr, nullptr, nullptr, nullptr, nullptr, nullptr, 0,
            rows, CF, IC, 3);
        // 3. vectorized depthwise convs (K + V in one pass over qk)
        dwconv_fast<<<bc * NM * 10, 256, 0, stream>>>(
            qk, wkT, convKb, wvT, convVb, kg, vg);
        // 4. LN stats
        stats_fused<<<rows / 4, 256, 0, stream>>>(qk, stats_qk, stats_x, rows);
        stats_kernel<<<(gm * 64 + 255) / 256, 256, 0, stream>>>(kg, IC, stats_kg, gm, IC);
        stats_kernel<<<(gm * 64 + 255) / 256, 256, 0, stream>>>(vg, IC, stats_vg, gm, DD);
        // 5. fused QKV projection (N=1536, BM=256) + glob tails
        gemm_mfma<256><<<dim3(TRI / 128, rows / 256 + gyg), 512, 0, stream>>>(
            qk, IC, stats_qk, stats_x, 1024, cs_qkv, b2_qkv, qkvW, nullptr, qkv,
            nullptr, nullptr, 0,
            kg, stats_kg, key_glob, vg, stats_vg, val_glob, gm,
            rows, TRI, IC, 2);
        // 6. attention
        attn_kernel<<<bc * NG * 8, 256, 0, stream>>>(qkv, key_glob, val_glob, attout);
        // 7. output projection (BM=256) -> d_out directly with dtype dispatch
        gemm_mfma<256><<<dim3(DD / 128, rows / 256), 512, 0, stream>>>(
            attout, DD, nullptr, nullptr, 0, nullptr, nullptr, WoT, bo, nullptr,
            d_out, flag, (long long)b0 * NSP * DD,
            nullptr, nullptr, nullptr, nullptr, nullptr, nullptr, 0,
            rows, DD, DD, 0);
    }
}

// Round 8
// 519.923 us; speedup vs baseline: 1.0329x; 1.0329x over previous
//
#include <hip/hip_runtime.h>
#include <hip/hip_bf16.h>

typedef __hip_bfloat16 bf16;
typedef __attribute__((ext_vector_type(8))) short bf16x8;
typedef __attribute__((ext_vector_type(8))) unsigned short ushort8;
typedef __attribute__((ext_vector_type(4))) float f32x4;

#define BT 8
#define HH 64
#define WW 64
#define NSP (HH*WW)          // 4096 spatial per batch
#define DD 512
#define CF 128
#define IC 640
#define NG 64                // windows per batch
#define NM 64                // global tokens per batch
#define TRI 1536             // fused qkv row stride
#define EPS 1e-5f

static __device__ __forceinline__ float b2f(bf16 v) { return __bfloat162float(v); }
static __device__ __forceinline__ bf16 f2b(float v) { return __float2bfloat16(v); }
static __device__ __forceinline__ float u2f(unsigned short u) {
    return __uint_as_float((unsigned)u << 16);
}
static __device__ __forceinline__ unsigned short f2u(float v) {
    bf16 b = __float2bfloat16(v);
    return __builtin_bit_cast(unsigned short, b);
}

// ---------------- dtype detector ----------------
__global__ void detect_dtype(const void* __restrict__ x, int* __restrict__ flag) {
    __shared__ int cnt;
    if (threadIdx.x == 0) cnt = 0;
    __syncthreads();
    const unsigned* w = (const unsigned*)x;
    int local = 0;
    for (int i = threadIdx.x; i < 4096; i += 256) {
        float v = __uint_as_float(w[i]);
        float a = fabsf(v);
        if (a > 1e-5f && a < 1e4f) local++;
    }
    atomicAdd(&cnt, local);
    __syncthreads();
    if (threadIdx.x == 0) *flag = (cnt > 2048) ? 1 : 0;   // 1 = fp32, 0 = bf16
}

// ---------------- canonicalize weights to bf16 ----------------
#define NW 20
struct WTab {
    const void* src[NW];
    int pre[NW + 1];
};

__global__ void convert_weights(WTab t, const int* __restrict__ flag,
                                bf16* __restrict__ dst, int total) {
    int fp32 = *flag;
    for (int idx = blockIdx.x * blockDim.x + threadIdx.x; idx < total;
         idx += gridDim.x * blockDim.x) {
        int seg = 0;
        #pragma unroll
        for (int i = 0; i < NW; ++i) if (idx >= t.pre[i + 1]) seg = i + 1;
        int local = idx - t.pre[seg];
        bf16 v;
        if (fp32) v = f2b(((const float*)t.src[seg])[local]);
        else      v = ((const bf16*)t.src[seg])[local];
        dst[idx] = v;
    }
}

// ------- transpose 7 weights: [R][C] -> [C][R] (with dst stride) ----------------
#define NSEG 7
struct TT {
    int srcoff[NSEG], dstoff[NSEG], R[NSEG], C[NSEG], dstride[NSEG], tpre[NSEG + 1];
};
__global__ void transpose_weights(const bf16* __restrict__ wc, bf16* __restrict__ wt, TT t) {
    __shared__ unsigned short tile[32][33];
    int tb = blockIdx.x;
    int seg = 0;
    while (tb >= t.tpre[seg + 1]) seg++;
    int lt = tb - t.tpre[seg];
    int C = t.C[seg];
    int tpr = C / 32;
    int r0 = (lt / tpr) * 32, c0 = (lt % tpr) * 32;
    int ds = t.dstride[seg];
    const unsigned short* src = (const unsigned short*)(wc + t.srcoff[seg]);
    unsigned short* dst = (unsigned short*)(wt + t.dstoff[seg]);
    int tx = threadIdx.x & 31, ty = threadIdx.x >> 5;  // 32 x 8
    #pragma unroll
    for (int i = 0; i < 4; ++i)
        tile[ty + i * 8][tx] = src[(long long)(r0 + ty + i * 8) * C + c0 + tx];
    __syncthreads();
    #pragma unroll
    for (int i = 0; i < 4; ++i)
        dst[(long long)(c0 + ty + i * 8) * ds + r0 + tx] = tile[tx][ty + i * 8];
}

// ------- fold LN gamma/beta into transposed weight (in place, zero-pad K tail) ---
__global__ void fold_ln_weights(bf16* __restrict__ WT, int stride,
                                const bf16* __restrict__ g,
                                const bf16* __restrict__ b, const bf16* __restrict__ bias,
                                float* __restrict__ colsum, float* __restrict__ bias2,
                                int K, int Kpad) {
    int n = blockIdx.x;
    bf16* wrow = WT + (long long)n * stride;
    float s1 = 0.f, s2 = 0.f;
    for (int k = threadIdx.x; k < K; k += 256) {
        float w = b2f(wrow[k]);
        float gk = b2f(g[k]);
        wrow[k] = f2b(w * gk);
        s1 += w * gk;
        s2 += w * b2f(b[k]);
    }
    for (int k = K + threadIdx.x; k < Kpad; k += 256) wrow[k] = f2b(0.f);
    __shared__ float r1[256], r2[256];
    r1[threadIdx.x] = s1; r2[threadIdx.x] = s2;
    __syncthreads();
    for (int off = 128; off > 0; off >>= 1) {
        if (threadIdx.x < off) {
            r1[threadIdx.x] += r1[threadIdx.x + off];
            r2[threadIdx.x] += r2[threadIdx.x + off];
        }
        __syncthreads();
    }
    if (threadIdx.x == 0) {
        colsum[n] = r1[0];
        bias2[n]  = b2f(bias[n]) + r2[0];
    }
}

// ---------------- assemble qk = [x | f], vectorized, dual dtype ----------------
__global__ void assemble_qk_v(const void* __restrict__ xv, const void* __restrict__ fv,
                              const int* __restrict__ flag, bf16* __restrict__ qk,
                              int rows, long long xoff, long long foff) {
    int fp32 = *flag;
    long long total = (long long)rows * 80;        // 80 groups of 8 per row
    for (long long i = (long long)blockIdx.x * blockDim.x + threadIdx.x; i < total;
         i += (long long)gridDim.x * blockDim.x) {
        int row = (int)(i / 80);
        int g = (int)(i % 80);
        ushort8 o;
        if (g < 64) {
            long long s = xoff + (long long)row * DD + g * 8;
            if (fp32) {
                const float* xp = (const float*)xv + s;
                #pragma unroll
                for (int e = 0; e < 8; ++e) o[e] = f2u(xp[e]);
            } else {
                o = *(const ushort8*)((const unsigned short*)xv + s);
            }
        } else {
            long long s = foff + (long long)row * CF + (g - 64) * 8;
            if (fp32) {
                const float* fp = (const float*)fv + s;
                #pragma unroll
                for (int e = 0; e < 8; ++e) o[e] = f2u(fp[e]);
            } else {
                o = *(const ushort8*)((const unsigned short*)fv + s);
            }
        }
        *(ushort8*)((unsigned short*)qk + (long long)row * IC + g * 8) = o;
    }
}

// ------- vectorized depthwise convs (weights pre-transposed to [p][c]) ----------
__global__ __launch_bounds__(256)
void dwconv_fast(const bf16* __restrict__ qk,
                 const bf16* __restrict__ wkT, const bf16* __restrict__ bk_,
                 const bf16* __restrict__ wvT, const bf16* __restrict__ bv_,
                 bf16* __restrict__ kg, bf16* __restrict__ vg) {
    int bid = blockIdx.x;
    int chunk = bid % 10;
    int bm = bid / 10;
    int b = bm >> 6, m = bm & 63;
    int my = m >> 3, mx = m & 7;
    int tid = threadIdx.x;
    int c8 = tid & 7;
    int pg = tid >> 3;            // 0..31
    int cbase = chunk * 64 + c8 * 8;
    const unsigned short* sb = (const unsigned short*)qk + (long long)b * NSP * IC;
    const unsigned short* wku = (const unsigned short*)wkT;
    const unsigned short* wvu = (const unsigned short*)wvT;
    bool doV = chunk < 8;
    float ak[8] = {0,0,0,0,0,0,0,0}, av[8] = {0,0,0,0,0,0,0,0};
    #pragma unroll
    for (int pp = 0; pp < 2; ++pp) {
        int p = pg + pp * 32;
        int ky = p >> 3, kx = p & 7;
        int pos = (my * 8 + ky) * WW + mx * 8 + kx;
        ushort8 q = *(const ushort8*)&sb[(long long)pos * IC + cbase];
        ushort8 wk8 = *(const ushort8*)&wku[p * IC + cbase];
        #pragma unroll
        for (int e = 0; e < 8; ++e) ak[e] += u2f(q[e]) * u2f(wk8[e]);
        if (doV) {
            ushort8 wv8 = *(const ushort8*)&wvu[p * DD + cbase];
            #pragma unroll
            for (int e = 0; e < 8; ++e) av[e] += u2f(q[e]) * u2f(wv8[e]);
        }
    }
    #pragma unroll
    for (int off = 8; off <= 32; off <<= 1) {
        #pragma unroll
        for (int e = 0; e < 8; ++e) {
            ak[e] += __shfl_xor(ak[e], off, 64);
            av[e] += __shfl_xor(av[e], off, 64);
        }
    }
    __shared__ float lds[2][4][8][8];
    int wave = tid >> 6, lane = tid & 63;
    if (lane < 8) {
        #pragma unroll
        for (int e = 0; e < 8; ++e) {
            lds[0][wave][lane][e] = ak[e];
            lds[1][wave][lane][e] = av[e];
        }
    }
    __syncthreads();
    if (tid < 64) {
        int cc8 = tid >> 3, e = tid & 7;
        int c = chunk * 64 + cc8 * 8 + e;
        float k4 = lds[0][0][cc8][e] + lds[0][1][cc8][e]
                 + lds[0][2][cc8][e] + lds[0][3][cc8][e];
        kg[(long long)bm * IC + c] = f2b(k4 + b2f(bk_[c]));
        if (doV) {
            float v4 = lds[1][0][cc8][e] + lds[1][1][cc8][e]
                     + lds[1][2][cc8][e] + lds[1][3][cc8][e];
            vg[(long long)bm * IC + c] = f2b(v4 + b2f(bv_[c]));
        } else {
            vg[(long long)bm * IC + c] = f2b(0.f);
        }
    }
}

// ---------------- fused LN stats over qk: [0,512) and [0,640) in one pass -------
__global__ void stats_fused(const bf16* __restrict__ qk, float* __restrict__ stats_full,
                            float* __restrict__ stats_x, int rows) {
    int gt = blockIdx.x * blockDim.x + threadIdx.x;
    int wid = gt >> 6;
    int lane = gt & 63;
    if (wid >= rows) return;
    const unsigned short* p = (const unsigned short*)qk + (long long)wid * IC;
    ushort8 v = *(const ushort8*)(p + lane * 8);
    float s1 = 0.f, ss1 = 0.f, s2 = 0.f, ss2 = 0.f;
    #pragma unroll
    for (int e = 0; e < 8; ++e) { float f = u2f(v[e]); s1 += f; ss1 += f * f; }
    if (lane < 16) {
        ushort8 v2 = *(const ushort8*)(p + DD + lane * 8);
        #pragma unroll
        for (int e = 0; e < 8; ++e) { float f = u2f(v2[e]); s2 += f; ss2 += f * f; }
    }
    #pragma unroll
    for (int off = 32; off > 0; off >>= 1) {
        s1  += __shfl_down(s1,  off, 64);
        ss1 += __shfl_down(ss1, off, 64);
        s2  += __shfl_down(s2,  off, 64);
        ss2 += __shfl_down(ss2, off, 64);
    }
    if (lane == 0) {
        float m1 = s1 / 512.f;
        float var1 = ss1 / 512.f - m1 * m1;
        stats_x[wid * 2]     = m1;
        stats_x[wid * 2 + 1] = rsqrtf(var1 + EPS);
        float st = s1 + s2, sst = ss1 + ss2;
        float m2 = st / 640.f;
        float var2 = sst / 640.f - m2 * m2;
        stats_full[wid * 2]     = m2;
        stats_full[wid * 2 + 1] = rsqrtf(var2 + EPS);
    }
}

// ---------------- LN stats (generic, for glob rows) ----------------
__global__ void stats_kernel(const bf16* __restrict__ X, int lda, float* __restrict__ stats,
                             int rows, int K) {
    int gt = blockIdx.x * blockDim.x + threadIdx.x;
    int wid = gt >> 6;
    int lane = gt & 63;
    if (wid >= rows) return;
    const bf16* p = X + (long long)wid * lda;
    float s = 0.f, ss = 0.f;
    for (int k = lane; k < K; k += 64) {
        float v = b2f(p[k]);
        s += v; ss += v * v;
    }
    #pragma unroll
    for (int off = 32; off > 0; off >>= 1) {
        s  += __shfl_down(s,  off, 64);
        ss += __shfl_down(ss, off, 64);
    }
    if (lane == 0) {
        float m = s / K;
        float var = ss / K - m * m;
        stats[wid * 2]     = m;
        stats[wid * 2 + 1] = rsqrtf(var + EPS);
    }
}

// ---- MFMA GEMM: 128x128 tile, BK=64, XOR-swizzled LDS, 4 waves -----------------
// LDS tiles [128 rows][64 cols bf16] = 128B rows. Swizzle: LDS 16B-slot (row, c)
// holds logical chunk c ^ (row&7); gload_lds dest is linear, so the global SOURCE
// is pre-swizzled (lane reads chunk (lane&7)^(lane>>3)); reads XOR back.
// Bmat TRANSPOSED: [N][K] row-major. M%128==0, N%128==0, K%64==0.
// mode 0: C = acc + bias
// mode 2: C = rstd*(acc - mean*colsum) + bias2; row stats = statsQK if col<nQK else statsX
// mode 3: qk[row][DD+col] *= sigmoid(acc + bias)  (flow+reweight fused; C = qk)
// outflag (main region, mode 0): write Cout fp32/bf16 per *outflag at outoff.
// Glob tails (A2k != null, mode 2): extra y-blocks; col [512,1024) -> A2k/stats2k/C2k,
// col [1024,1536) -> A2v/stats2v/C2v; col<512 idle. A2/stats2 padded to +128 rows.
__global__ __launch_bounds__(256)
void gemm_mfma(const bf16* __restrict__ A, int lda,
               const float* __restrict__ statsQK, const float* __restrict__ statsX,
               int nQK,
               const float* __restrict__ colsum, const float* __restrict__ bias2,
               const bf16* __restrict__ Bmat,
               const bf16* __restrict__ bias,
               bf16* __restrict__ C,
               void* __restrict__ Cout, const int* __restrict__ outflag, long long outoff,
               const bf16* __restrict__ A2k, const float* __restrict__ stats2k,
               bf16* __restrict__ C2k,
               const bf16* __restrict__ A2v, const float* __restrict__ stats2v,
               bf16* __restrict__ C2v, int M2,
               int M, int N, int K, int mode) {
    __shared__ unsigned short As[128 * 64];   // [m][kc] swizzled, 128B rows
    __shared__ unsigned short Bs[128 * 64];   // [n][kc] swizzled
    int tid = threadIdx.x;

    // general bijective XCD-chunked swizzle (m204)
    int nwgx = gridDim.x;
    int nwg = nwgx * gridDim.y;
    int orig = blockIdx.y * nwgx + blockIdx.x;
    int qq = nwg >> 3, rr = nwg & 7;
    int xcd = orig & 7, idx = orig >> 3;
    int wg = (xcd < rr ? xcd * (qq + 1) : rr * (qq + 1) + (xcd - rr) * qq) + idx;
    int gy = wg / nwgx;
    int gx = wg % nwgx;
    int bn = gx * 128;

    int nby_main = M >> 7;
    const bf16* Ap;
    const float* stp = nullptr;
    bf16* C2 = nullptr;
    int rowbase, mlim, glob, colOff = 0;
    if (gy < nby_main) {
        Ap = A; rowbase = gy * 128; mlim = M; glob = 0;
        if (mode == 2) stp = (bn >= nQK) ? statsX : statsQK;
    } else {
        if (bn < 512) return;                 // no Q projection for glob rows
        int isV = bn >= 1024;
        Ap = isV ? A2v : A2k;
        stp = isV ? stats2v : stats2k;
        C2 = isV ? C2v : C2k;
        colOff = isV ? 1024 : 512;
        rowbase = (gy - nby_main) * 128; mlim = M2; glob = 1;
    }

    int wave = tid >> 6, lane = tid & 63;
    int qm = (wave >> 1) * 64;
    int qn = (wave & 1) * 64;
    int lm = lane & 15;
    int kqh = lane >> 4;            // 0..3: 16B sub-chunk within a 32-elem half
    int sr = lane >> 3;             // 0..7: row within 8-row stage segment
    int scg = ((lane & 7) ^ sr) * 8;   // pre-swizzled global col (shorts)

    f32x4 acc[4][4];
    #pragma unroll
    for (int i = 0; i < 4; ++i)
        #pragma unroll
        for (int j = 0; j < 4; ++j)
            acc[i][j] = (f32x4){0.f, 0.f, 0.f, 0.f};

    const unsigned short* Au = (const unsigned short*)Ap;
    const unsigned short* Bu = (const unsigned short*)Bmat;

    for (int k0 = 0; k0 < K; k0 += 64) {
        // stage A + B: 16 segments each of (8 rows x 64 cols); wave w does 4 + 4.
        #pragma unroll
        for (int i = 0; i < 4; ++i) {
            int seg = wave * 4 + i;
            const unsigned short* gp =
                Au + (long long)(rowbase + seg * 8 + sr) * lda + k0 + scg;
            __builtin_amdgcn_global_load_lds(
                (const __attribute__((address_space(1))) void*)gp,
                (__attribute__((address_space(3))) void*)&As[seg * 512], 16, 0, 0);
        }
        #pragma unroll
        for (int i = 0; i < 4; ++i) {
            int seg = wave * 4 + i;
            const unsigned short* gp =
                Bu + (long long)(bn + seg * 8 + sr) * K + k0 + scg;
            __builtin_amdgcn_global_load_lds(
                (const __attribute__((address_space(1))) void*)gp,
                (__attribute__((address_space(3))) void*)&Bs[seg * 512], 16, 0, 0);
        }
        __syncthreads();
        #pragma unroll
        for (int ks = 0; ks < 2; ++ks) {
            bf16x8 af[4], bfr[4];
            int kc = ks * 4 + kqh;       // logical 16B chunk 0..7
            #pragma unroll
            for (int i = 0; i < 4; ++i) {
                int R = qm + i * 16 + lm;
                af[i] = *(const bf16x8*)&As[R * 64 + ((kc ^ (R & 7)) << 3)];
            }
            #pragma unroll
            for (int j = 0; j < 4; ++j) {
                int R = qn + j * 16 + lm;
                bfr[j] = *(const bf16x8*)&Bs[R * 64 + ((kc ^ (R & 7)) << 3)];
            }
            #pragma unroll
            for (int i = 0; i < 4; ++i)
                #pragma unroll
                for (int j = 0; j < 4; ++j)
                    acc[i][j] = __builtin_amdgcn_mfma_f32_16x16x32_bf16(
                        af[i], bfr[j], acc[i][j], 0, 0, 0);
        }
        __syncthreads();
    }

    // ---- epilogue: C/D layout col=lane&15, row=(lane>>4)*4+reg ----
    int rq = (lane >> 4) * 4;
    float cs[4], bb[4];
    #pragma unroll
    for (int j = 0; j < 4; ++j) {
        int col = bn + qn + j * 16 + lm;
        if (mode == 2) { cs[j] = colsum[col]; bb[j] = bias2[col]; }
        else bb[j] = bias ? b2f(bias[col]) : 0.f;
    }
    int ofp = (!glob && outflag) ? *outflag : 0;
    #pragma unroll
    for (int i = 0; i < 4; ++i) {
        #pragma unroll
        for (int r = 0; r < 4; ++r) {
            int row = rowbase + qm + i * 16 + rq + r;
            if (row >= mlim) continue;
            float mean = 0.f, rstd = 0.f;
            if (mode == 2) { mean = stp[row * 2]; rstd = stp[row * 2 + 1]; }
            #pragma unroll
            for (int j = 0; j < 4; ++j) {
                int col = bn + qn + j * 16 + lm;
                float v = acc[i][j][r];
                if (mode == 2) v = rstd * (v - mean * cs[j]) + bb[j];
                else {
                    v += bb[j];
                    if (mode == 3) v = 1.f / (1.f + __expf(-v));
                }
                if (mode == 3) {
                    unsigned short* qp =
                        (unsigned short*)C + (long long)row * IC + DD + col;
                    *qp = f2u(u2f(*qp) * v);
                    continue;
                }
                if (glob) {
                    C2[(long long)row * 512 + (col - colOff)] = f2b(v);
                } else if (outflag) {
                    long long ci = (long long)row * N + col;
                    if (ofp) ((float*)Cout)[outoff + ci] = v;
                    else     ((bf16*)Cout)[outoff + ci] = f2b(v);
                } else {
                    C[(long long)row * N + col] = f2b(v);
                }
            }
        }
    }
}

// ---------------- MFMA attention (qkv fused input, stride TRI) ----------------
#define QS_STRIDE 72
#define PS_STRIDE 136
__global__ __launch_bounds__(256)
void attn_kernel(const bf16* __restrict__ qkv,
                 const bf16* __restrict__ key_glob, const bf16* __restrict__ val_glob,
                 bf16* __restrict__ attout) {
    int h = blockIdx.x & 7;
    int g = (blockIdx.x >> 3) & 63;
    int b = blockIdx.x >> 9;
    int gy = g >> 3, gx = g & 7;

    __shared__ unsigned short smem[64 * PS_STRIDE + 64 * PS_STRIDE];
    unsigned short* Qs = smem;                       // [64][QS_STRIDE]
    unsigned short* Ks = smem + 64 * QS_STRIDE;      // [128][QS_STRIDE]
    unsigned short* Ps = smem;                       // [64][PS_STRIDE]
    unsigned short* Vs = smem + 64 * PS_STRIDE;      // [64][PS_STRIDE] (d-major: [d][t])

    int tid = threadIdx.x;
    const unsigned short* QKV = (const unsigned short*)qkv;
    const unsigned short* KG = (const unsigned short*)key_glob;
    const unsigned short* VG = (const unsigned short*)val_glob;

    #pragma unroll
    for (int it = 0; it < 2; ++it) {
        int i = tid + it * 256;        // 512 units
        int t = i >> 3, dg = (i & 7) * 8;
        int ty = t >> 3, tx = t & 7;
        long long row = (long long)b * NSP + (gy * 8 + ty) * WW + gx * 8 + tx;
        *(ushort8*)&Qs[t * QS_STRIDE + dg] =
            *(const ushort8*)&QKV[row * TRI + h * 64 + dg];
    }
    #pragma unroll
    for (int it = 0; it < 4; ++it) {
        int i = tid + it * 256;        // 1024 units
        int t = i >> 3, dg = (i & 7) * 8;
        ushort8 kv;
        if (t < 64) {
            int ty = t >> 3, tx = t & 7;
            long long row = (long long)b * NSP + (gy * 8 + ty) * WW + gx * 8 + tx;
            kv = *(const ushort8*)&QKV[row * TRI + 512 + h * 64 + dg];
        } else {
            long long srow = (long long)b * NM + (t - 64);
            kv = *(const ushort8*)&KG[srow * DD + h * 64 + dg];
        }
        *(ushort8*)&Ks[t * QS_STRIDE + dg] = kv;
    }
    __syncthreads();

    int wave = tid >> 6, lane = tid & 63;
    int m0 = wave * 16;
    int lm = lane & 15;
    int quad = lane >> 4;            // 0..3

    f32x4 sacc[8];
    #pragma unroll
    for (int j = 0; j < 8; ++j) sacc[j] = (f32x4){0.f, 0.f, 0.f, 0.f};
    #pragma unroll
    for (int ks = 0; ks < 2; ++ks) {
        int kq = quad * 8 + ks * 32;
        bf16x8 af = *(const bf16x8*)&Qs[(m0 + lm) * QS_STRIDE + kq];
        #pragma unroll
        for (int j = 0; j < 8; ++j) {
            bf16x8 bfr = *(const bf16x8*)&Ks[(j * 16 + lm) * QS_STRIDE + kq];
            sacc[j] = __builtin_amdgcn_mfma_f32_16x16x32_bf16(af, bfr, sacc[j], 0, 0, 0);
        }
    }
    float pinv[4];
    #pragma unroll
    for (int r = 0; r < 4; ++r) {
        float mx = -1e30f;
        #pragma unroll
        for (int j = 0; j < 8; ++j) {
            sacc[j][r] *= 0.125f;
            mx = fmaxf(mx, sacc[j][r]);
        }
        mx = fmaxf(mx, __shfl_xor(mx, 1, 64));
        mx = fmaxf(mx, __shfl_xor(mx, 2, 64));
        mx = fmaxf(mx, __shfl_xor(mx, 4, 64));
        mx = fmaxf(mx, __shfl_xor(mx, 8, 64));
        float l = 0.f;
        #pragma unroll
        for (int j = 0; j < 8; ++j) {
            float p = __expf(sacc[j][r] - mx);
            sacc[j][r] = p;
            l += p;
        }
        l += __shfl_xor(l, 1, 64);
        l += __shfl_xor(l, 2, 64);
        l += __shfl_xor(l, 4, 64);
        l += __shfl_xor(l, 8, 64);
        pinv[r] = 1.f / l;
    }
    __syncthreads();   // all waves done reading Qs/Ks

    #pragma unroll
    for (int r = 0; r < 4; ++r) {
        int qrow = m0 + quad * 4 + r;
        #pragma unroll
        for (int j = 0; j < 8; ++j)
            Ps[qrow * PS_STRIDE + j * 16 + lm] = f2u(sacc[j][r] * pinv[r]);
    }
    #pragma unroll
    for (int it = 0; it < 4; ++it) {
        int i = tid + it * 256;        // 1024 units: t=128, dg=8
        int t = i & 127, dg = (i >> 7) * 8;
        ushort8 v;
        if (t < 64) {
            int ty = t >> 3, tx = t & 7;
            long long row = (long long)b * NSP + (gy * 8 + ty) * WW + gx * 8 + tx;
            v = *(const ushort8*)&QKV[row * TRI + 1024 + h * 64 + dg];
        } else {
            long long srow = (long long)b * NM + (t - 64);
            v = *(const ushort8*)&VG[srow * DD + h * 64 + dg];
        }
        #pragma unroll
        for (int e = 0; e < 8; ++e) Vs[(dg + e) * PS_STRIDE + t] = v[e];
    }
    __syncthreads();

    f32x4 oacc[4];
    #pragma unroll
    for (int j = 0; j < 4; ++j) oacc[j] = (f32x4){0.f, 0.f, 0.f, 0.f};
    #pragma unroll
    for (int ks = 0; ks < 4; ++ks) {
        int kq = quad * 8 + ks * 32;
        bf16x8 af = *(const bf16x8*)&Ps[(m0 + lm) * PS_STRIDE + kq];
        #pragma unroll
        for (int j = 0; j < 4; ++j) {
            bf16x8 bfr = *(const bf16x8*)&Vs[(j * 16 + lm) * PS_STRIDE + kq];
            oacc[j] = __builtin_amdgcn_mfma_f32_16x16x32_bf16(af, bfr, oacc[j], 0, 0, 0);
        }
    }
    #pragma unroll
    for (int r = 0; r < 4; ++r) {
        int qrow = m0 + quad * 4 + r;
        int ty = qrow >> 3, tx = qrow & 7;
        long long orow = (long long)b * NSP + (gy * 8 + ty) * WW + gx * 8 + tx;
        unsigned short* op = (unsigned short*)attout + orow * DD + h * 64;
        #pragma unroll
        for (int j = 0; j < 4; ++j)
            op[j * 16 + lm] = f2u(oacc[j][r]);
    }
}

static inline size_t alg(size_t b) { return (b + 255) & ~(size_t)255; }

extern "C" void kernel_launch(void* const* d_in, const int* in_sizes, int n_in,
                              void* d_out, int out_size, void* d_ws, size_t ws_size,
                              hipStream_t stream) {
    int s = (n_in > 2 && in_sizes[2] == 1) ? 0 : -1;

    const void* xv = d_in[0];
    const void* fv = d_in[1];
    const void* wsrc[NW];
    for (int i = 0; i < NW; ++i) wsrc[i] = d_in[3 + s + i];
    (void)out_size;

    const int wcnt[NW] = {327680, 512, 327680, 512, 262144, 512, 262144, 512,
                          40960, 640, 32768, 512, 640, 640, 640, 640, 512, 512,
                          81920, 128};
    WTab tab;
    int pre = 0;
    for (int i = 0; i < NW; ++i) {
        tab.src[i] = wsrc[i];
        tab.pre[i] = pre;
        pre += wcnt[i];
    }
    tab.pre[NW] = pre;
    const int wtotal = pre;

    char* ws = (char*)d_ws;
    size_t head = 0;
    int* flag = (int*)(ws + head); head += 256;
    bf16* wc = (bf16*)(ws + head); head += alg((size_t)wtotal * 2);
    // transposed weights: qkvW [1536][640] | WoT [512][512] | rwT [128][640]
    //                     | wkT [64][640] | wvT [64][512]
    const int off_qkvW = 0;
    const int off_WoT  = TRI * IC;                 // 983040
    const int off_rwT  = off_WoT + DD * DD;        // 1245184
    const int off_wkT  = off_rwT + CF * IC;        // 1327104
    const int off_wvT  = off_wkT + 64 * IC;        // 1368064
    const int wtpre    = off_wvT + 64 * DD;        // 1400832
    bf16* wt = (bf16*)(ws + head); head += alg((size_t)wtpre * 2);
    float* foldv = (float*)(ws + head); head += alg(2 * TRI * sizeof(float));
    float* cs_qkv = foldv;
    float* b2_qkv = foldv + TRI;

    const bf16* bq     = wc + tab.pre[1];
    const bf16* bk     = wc + tab.pre[3];
    const bf16* bv     = wc + tab.pre[5];
    const bf16* bo     = wc + tab.pre[7];
    const bf16* convKb = wc + tab.pre[9];
    const bf16* convVb = wc + tab.pre[11];
    const bf16* qn_g   = wc + tab.pre[12];
    const bf16* qn_b   = wc + tab.pre[13];
    const bf16* kn_g   = wc + tab.pre[14];
    const bf16* kn_b   = wc + tab.pre[15];
    const bf16* vn_g   = wc + tab.pre[16];
    const bf16* vn_b   = wc + tab.pre[17];
    const bf16* rw_b   = wc + tab.pre[19];
    bf16* qkvW = wt + off_qkvW;
    bf16* WoT  = wt + off_WoT;
    bf16* rwT  = wt + off_rwT;
    bf16* wkT  = wt + off_wkT;
    bf16* wvT  = wt + off_wvT;

    size_t avail = ws_size > head ? ws_size - head : 0;
    auto need = [&](int bc) -> size_t {
        size_t rows = (size_t)bc * NSP;
        size_t gm = (size_t)bc * NM, gmp = gm + 128;
        return alg(rows * IC * 2) + alg(rows * TRI * 2)
             + 2 * alg(gmp * IC * 2) + 2 * alg(gm * DD * 2)
             + 2 * alg(rows * 8) + 2 * alg(gmp * 8);
    };
    int nb = BT;
    while (nb > 1 && need(nb) > avail) nb--;

    detect_dtype<<<1, 256, 0, stream>>>(xv, flag);
    convert_weights<<<(wtotal + 255) / 256, 256, 0, stream>>>(tab, flag, wc, wtotal);
    {
        TT tt;
        const int srcsel[NSEG] = {0, 2, 4, 6, 18, 8, 10};
        const int Rr[NSEG]     = {IC, IC, DD, DD, IC, IC, DD};
        const int Cc[NSEG]     = {DD, DD, DD, DD, CF, 64, 64};
        const int dof[NSEG]    = {0, DD * IC, 2 * DD * IC, off_WoT, off_rwT,
                                  off_wkT, off_wvT};
        const int dstr[NSEG]   = {IC, IC, IC, DD, IC, IC, DD};
        int tp = 0;
        for (int i = 0; i < NSEG; ++i) {
            tt.srcoff[i] = tab.pre[srcsel[i]];
            tt.dstoff[i] = dof[i];
            tt.R[i] = Rr[i];
            tt.C[i] = Cc[i];
            tt.dstride[i] = dstr[i];
            tt.tpre[i] = tp;
            tp += (Rr[i] / 32) * (Cc[i] / 32);
        }
        tt.tpre[NSEG] = tp;
        transpose_weights<<<tp, 256, 0, stream>>>(wc, wt, tt);
    }
    // fold LN into qkvW rows; V region zero-padded in K to 640
    fold_ln_weights<<<DD, 256, 0, stream>>>(qkvW,              IC, qn_g, qn_b, bq,
                                            cs_qkv,       b2_qkv,       IC, IC);
    fold_ln_weights<<<DD, 256, 0, stream>>>(qkvW + DD * IC,    IC, kn_g, kn_b, bk,
                                            cs_qkv + 512, b2_qkv + 512, IC, IC);
    fold_ln_weights<<<DD, 256, 0, stream>>>(qkvW + 2 * DD * IC, IC, vn_g, vn_b, bv,
                                            cs_qkv + 1024, b2_qkv + 1024, DD, IC);

    for (int b0 = 0; b0 < BT; b0 += nb) {
        int bc = BT - b0 < nb ? BT - b0 : nb;
        int rows = bc * NSP;
        int gm = bc * NM;           // glob rows this chunk
        int gyg = (gm + 127) / 128; // extra y-blocks for glob tail

        size_t off = head;
        auto alloc = [&](size_t bytes) -> void* {
            void* p = ws + off; off += alg(bytes); return p;
        };
        size_t gmp = (size_t)gm + 128;  // padded for OOB staging reads
        bf16* qk        = (bf16*)alloc((size_t)rows * IC * 2);
        bf16* qkv       = (bf16*)alloc((size_t)rows * TRI * 2);
        bf16* kg        = (bf16*)alloc(gmp * IC * 2);
        bf16* vg        = (bf16*)alloc(gmp * IC * 2);   // stride IC, cols 512.. zeroed
        bf16* key_glob  = (bf16*)alloc((size_t)gm * DD * 2);
        bf16* val_glob  = (bf16*)alloc((size_t)gm * DD * 2);
        float* stats_qk = (float*)alloc((size_t)rows * 8);
        float* stats_x  = (float*)alloc((size_t)rows * 8);
        float* stats_kg = (float*)alloc(gmp * 8);
        float* stats_vg = (float*)alloc(gmp * 8);
        bf16* attout    = qk;        // alias: qk dead after fused QKV GEMM

        // 1. assemble qk = [x | f]
        {
            long long total = (long long)rows * 80;
            int blocks = (int)((total + 255) / 256);
            assemble_qk_v<<<blocks, 256, 0, stream>>>(
                xv, fv, flag, qk, rows,
                (long long)b0 * NSP * DD, (long long)b0 * NSP * CF);
        }
        // 2. flow gemm + reweight fused (mode 3): qk.f *= sigmoid(qk @ rw_W + rw_b)
        gemm_mfma<<<dim3(CF / 128, rows / 128), 256, 0, stream>>>(
            qk, IC, nullptr, nullptr, 0, nullptr, nullptr, rwT, rw_b, qk,
            nullptr, nullptr, 0,
            nullptr, nullptr, nullptr, nullptr, nullptr, nullptr, 0,
            rows, CF, IC, 3);
        // 3. vectorized depthwise convs (K + V in one pass over qk)
        dwconv_fast<<<bc * NM * 10, 256, 0, stream>>>(
            qk, wkT, convKb, wvT, convVb, kg, vg);
        // 4. LN stats
        stats_fused<<<rows / 4, 256, 0, stream>>>(qk, stats_qk, stats_x, rows);
        stats_kernel<<<(gm * 64 + 255) / 256, 256, 0, stream>>>(kg, IC, stats_kg, gm, IC);
        stats_kernel<<<(gm * 64 + 255) / 256, 256, 0, stream>>>(vg, IC, stats_vg, gm, DD);
        // 5. fused QKV projection (N=1536) + glob tails
        gemm_mfma<<<dim3(TRI / 128, rows / 128 + gyg), 256, 0, stream>>>(
            qk, IC, stats_qk, stats_x, 1024, cs_qkv, b2_qkv, qkvW, nullptr, qkv,
            nullptr, nullptr, 0,
            kg, stats_kg, key_glob, vg, stats_vg, val_glob, gm,
            rows, TRI, IC, 2);
        // 6. attention
        attn_kernel<<<bc * NG * 8, 256, 0, stream>>>(qkv, key_glob, val_glob, attout);
        // 7. output projection -> d_out directly with dtype dispatch
        gemm_mfma<<<dim3(DD / 128, rows / 128), 256, 0, stream>>>(
            attout, DD, nullptr, nullptr, 0, nullptr, nullptr, WoT, bo, nullptr,
            d_out, flag, (long long)b0 * NSP * DD,
            nullptr, nullptr, nullptr, nullptr, nullptr, nullptr, 0,
            rows, DD, DD, 0);
    }
}

// Round 9
// 493.497 us; speedup vs baseline: 1.0882x; 1.0535x over previous
//
#include <hip/hip_runtime.h>
#include <hip/hip_bf16.h>

typedef __hip_bfloat16 bf16;
typedef __attribute__((ext_vector_type(8))) short bf16x8;
typedef __attribute__((ext_vector_type(8))) unsigned short ushort8;
typedef __attribute__((ext_vector_type(4))) float f32x4;

#define BT 8
#define HH 64
#define WW 64
#define NSP (HH*WW)          // 4096 spatial per batch
#define DD 512
#define CF 128
#define IC 640
#define NG 64                // windows per batch
#define NM 64                // global tokens per batch
#define TRI 1536             // fused qkv row stride
#define EPS 1e-5f

static __device__ __forceinline__ float b2f(bf16 v) { return __bfloat162float(v); }
static __device__ __forceinline__ bf16 f2b(float v) { return __float2bfloat16(v); }
static __device__ __forceinline__ float u2f(unsigned short u) {
    return __uint_as_float((unsigned)u << 16);
}
static __device__ __forceinline__ unsigned short f2u(float v) {
    bf16 b = __float2bfloat16(v);
    return __builtin_bit_cast(unsigned short, b);
}

// ---------------- dtype detector ----------------
__global__ void detect_dtype(const void* __restrict__ x, int* __restrict__ flag) {
    __shared__ int cnt;
    if (threadIdx.x == 0) cnt = 0;
    __syncthreads();
    const unsigned* w = (const unsigned*)x;
    int local = 0;
    for (int i = threadIdx.x; i < 4096; i += 256) {
        float v = __uint_as_float(w[i]);
        float a = fabsf(v);
        if (a > 1e-5f && a < 1e4f) local++;
    }
    atomicAdd(&cnt, local);
    __syncthreads();
    if (threadIdx.x == 0) *flag = (cnt > 2048) ? 1 : 0;   // 1 = fp32, 0 = bf16
}

// ---------------- canonicalize weights to bf16 ----------------
#define NW 20
struct WTab {
    const void* src[NW];
    int pre[NW + 1];
};

__global__ void convert_weights(WTab t, const int* __restrict__ flag,
                                bf16* __restrict__ dst, int total) {
    int fp32 = *flag;
    for (int idx = blockIdx.x * blockDim.x + threadIdx.x; idx < total;
         idx += gridDim.x * blockDim.x) {
        int seg = 0;
        #pragma unroll
        for (int i = 0; i < NW; ++i) if (idx >= t.pre[i + 1]) seg = i + 1;
        int local = idx - t.pre[seg];
        bf16 v;
        if (fp32) v = f2b(((const float*)t.src[seg])[local]);
        else      v = ((const bf16*)t.src[seg])[local];
        dst[idx] = v;
    }
}

// ------- transpose 7 weights: [R][C] -> [C][R] (with dst stride) ----------------
#define NSEG 7
struct TT {
    int srcoff[NSEG], dstoff[NSEG], R[NSEG], C[NSEG], dstride[NSEG], tpre[NSEG + 1];
};
__global__ void transpose_weights(const bf16* __restrict__ wc, bf16* __restrict__ wt, TT t) {
    __shared__ unsigned short tile[32][33];
    int tb = blockIdx.x;
    int seg = 0;
    while (tb >= t.tpre[seg + 1]) seg++;
    int lt = tb - t.tpre[seg];
    int C = t.C[seg];
    int tpr = C / 32;
    int r0 = (lt / tpr) * 32, c0 = (lt % tpr) * 32;
    int ds = t.dstride[seg];
    const unsigned short* src = (const unsigned short*)(wc + t.srcoff[seg]);
    unsigned short* dst = (unsigned short*)(wt + t.dstoff[seg]);
    int tx = threadIdx.x & 31, ty = threadIdx.x >> 5;  // 32 x 8
    #pragma unroll
    for (int i = 0; i < 4; ++i)
        tile[ty + i * 8][tx] = src[(long long)(r0 + ty + i * 8) * C + c0 + tx];
    __syncthreads();
    #pragma unroll
    for (int i = 0; i < 4; ++i)
        dst[(long long)(c0 + ty + i * 8) * ds + r0 + tx] = tile[tx][ty + i * 8];
}

// ------- fold LN gamma/beta into transposed weight (in place, zero-pad K tail) ---
__global__ void fold_ln_weights(bf16* __restrict__ WT, int stride,
                                const bf16* __restrict__ g,
                                const bf16* __restrict__ b, const bf16* __restrict__ bias,
                                float* __restrict__ colsum, float* __restrict__ bias2,
                                int K, int Kpad) {
    int n = blockIdx.x;
    bf16* wrow = WT + (long long)n * stride;
    float s1 = 0.f, s2 = 0.f;
    for (int k = threadIdx.x; k < K; k += 256) {
        float w = b2f(wrow[k]);
        float gk = b2f(g[k]);
        wrow[k] = f2b(w * gk);
        s1 += w * gk;
        s2 += w * b2f(b[k]);
    }
    for (int k = K + threadIdx.x; k < Kpad; k += 256) wrow[k] = f2b(0.f);
    __shared__ float r1[256], r2[256];
    r1[threadIdx.x] = s1; r2[threadIdx.x] = s2;
    __syncthreads();
    for (int off = 128; off > 0; off >>= 1) {
        if (threadIdx.x < off) {
            r1[threadIdx.x] += r1[threadIdx.x + off];
            r2[threadIdx.x] += r2[threadIdx.x + off];
        }
        __syncthreads();
    }
    if (threadIdx.x == 0) {
        colsum[n] = r1[0];
        bias2[n]  = b2f(bias[n]) + r2[0];
    }
}

// ---------------- assemble qk = [x | f], vectorized, dual dtype ----------------
__global__ void assemble_qk_v(const void* __restrict__ xv, const void* __restrict__ fv,
                              const int* __restrict__ flag, bf16* __restrict__ qk,
                              int rows, long long xoff, long long foff) {
    int fp32 = *flag;
    long long total = (long long)rows * 80;        // 80 groups of 8 per row
    for (long long i = (long long)blockIdx.x * blockDim.x + threadIdx.x; i < total;
         i += (long long)gridDim.x * blockDim.x) {
        int row = (int)(i / 80);
        int g = (int)(i % 80);
        ushort8 o;
        if (g < 64) {
            long long s = xoff + (long long)row * DD + g * 8;
            if (fp32) {
                const float* xp = (const float*)xv + s;
                #pragma unroll
                for (int e = 0; e < 8; ++e) o[e] = f2u(xp[e]);
            } else {
                o = *(const ushort8*)((const unsigned short*)xv + s);
            }
        } else {
            long long s = foff + (long long)row * CF + (g - 64) * 8;
            if (fp32) {
                const float* fp = (const float*)fv + s;
                #pragma unroll
                for (int e = 0; e < 8; ++e) o[e] = f2u(fp[e]);
            } else {
                o = *(const ushort8*)((const unsigned short*)fv + s);
            }
        }
        *(ushort8*)((unsigned short*)qk + (long long)row * IC + g * 8) = o;
    }
}

// ------- vectorized depthwise convs (weights pre-transposed to [p][c]) ----------
__global__ __launch_bounds__(256)
void dwconv_fast(const bf16* __restrict__ qk,
                 const bf16* __restrict__ wkT, const bf16* __restrict__ bk_,
                 const bf16* __restrict__ wvT, const bf16* __restrict__ bv_,
                 bf16* __restrict__ kg, bf16* __restrict__ vg) {
    int bid = blockIdx.x;
    int chunk = bid % 10;
    int bm = bid / 10;
    int b = bm >> 6, m = bm & 63;
    int my = m >> 3, mx = m & 7;
    int tid = threadIdx.x;
    int c8 = tid & 7;
    int pg = tid >> 3;            // 0..31
    int cbase = chunk * 64 + c8 * 8;
    const unsigned short* sb = (const unsigned short*)qk + (long long)b * NSP * IC;
    const unsigned short* wku = (const unsigned short*)wkT;
    const unsigned short* wvu = (const unsigned short*)wvT;
    bool doV = chunk < 8;
    float ak[8] = {0,0,0,0,0,0,0,0}, av[8] = {0,0,0,0,0,0,0,0};
    #pragma unroll
    for (int pp = 0; pp < 2; ++pp) {
        int p = pg + pp * 32;
        int ky = p >> 3, kx = p & 7;
        int pos = (my * 8 + ky) * WW + mx * 8 + kx;
        ushort8 q = *(const ushort8*)&sb[(long long)pos * IC + cbase];
        ushort8 wk8 = *(const ushort8*)&wku[p * IC + cbase];
        #pragma unroll
        for (int e = 0; e < 8; ++e) ak[e] += u2f(q[e]) * u2f(wk8[e]);
        if (doV) {
            ushort8 wv8 = *(const ushort8*)&wvu[p * DD + cbase];
            #pragma unroll
            for (int e = 0; e < 8; ++e) av[e] += u2f(q[e]) * u2f(wv8[e]);
        }
    }
    #pragma unroll
    for (int off = 8; off <= 32; off <<= 1) {
        #pragma unroll
        for (int e = 0; e < 8; ++e) {
            ak[e] += __shfl_xor(ak[e], off, 64);
            av[e] += __shfl_xor(av[e], off, 64);
        }
    }
    __shared__ float lds[2][4][8][8];
    int wave = tid >> 6, lane = tid & 63;
    if (lane < 8) {
        #pragma unroll
        for (int e = 0; e < 8; ++e) {
            lds[0][wave][lane][e] = ak[e];
            lds[1][wave][lane][e] = av[e];
        }
    }
    __syncthreads();
    if (tid < 64) {
        int cc8 = tid >> 3, e = tid & 7;
        int c = chunk * 64 + cc8 * 8 + e;
        float k4 = lds[0][0][cc8][e] + lds[0][1][cc8][e]
                 + lds[0][2][cc8][e] + lds[0][3][cc8][e];
        kg[(long long)bm * IC + c] = f2b(k4 + b2f(bk_[c]));
        if (doV) {
            float v4 = lds[1][0][cc8][e] + lds[1][1][cc8][e]
                     + lds[1][2][cc8][e] + lds[1][3][cc8][e];
            vg[(long long)bm * IC + c] = f2b(v4 + b2f(bv_[c]));
        } else {
            vg[(long long)bm * IC + c] = f2b(0.f);
        }
    }
}

// ---------------- fused LN stats over qk: [0,512) and [0,640) in one pass -------
__global__ void stats_fused(const bf16* __restrict__ qk, float* __restrict__ stats_full,
                            float* __restrict__ stats_x, int rows) {
    int gt = blockIdx.x * blockDim.x + threadIdx.x;
    int wid = gt >> 6;
    int lane = gt & 63;
    if (wid >= rows) return;
    const unsigned short* p = (const unsigned short*)qk + (long long)wid * IC;
    ushort8 v = *(const ushort8*)(p + lane * 8);
    float s1 = 0.f, ss1 = 0.f, s2 = 0.f, ss2 = 0.f;
    #pragma unroll
    for (int e = 0; e < 8; ++e) { float f = u2f(v[e]); s1 += f; ss1 += f * f; }
    if (lane < 16) {
        ushort8 v2 = *(const ushort8*)(p + DD + lane * 8);
        #pragma unroll
        for (int e = 0; e < 8; ++e) { float f = u2f(v2[e]); s2 += f; ss2 += f * f; }
    }
    #pragma unroll
    for (int off = 32; off > 0; off >>= 1) {
        s1  += __shfl_down(s1,  off, 64);
        ss1 += __shfl_down(ss1, off, 64);
        s2  += __shfl_down(s2,  off, 64);
        ss2 += __shfl_down(ss2, off, 64);
    }
    if (lane == 0) {
        float m1 = s1 / 512.f;
        float var1 = ss1 / 512.f - m1 * m1;
        stats_x[wid * 2]     = m1;
        stats_x[wid * 2 + 1] = rsqrtf(var1 + EPS);
        float st = s1 + s2, sst = ss1 + ss2;
        float m2 = st / 640.f;
        float var2 = sst / 640.f - m2 * m2;
        stats_full[wid * 2]     = m2;
        stats_full[wid * 2 + 1] = rsqrtf(var2 + EPS);
    }
}

// ---------------- LN stats (generic, for glob rows) ----------------
__global__ void stats_kernel(const bf16* __restrict__ X, int lda, float* __restrict__ stats,
                             int rows, int K) {
    int gt = blockIdx.x * blockDim.x + threadIdx.x;
    int wid = gt >> 6;
    int lane = gt & 63;
    if (wid >= rows) return;
    const bf16* p = X + (long long)wid * lda;
    float s = 0.f, ss = 0.f;
    for (int k = lane; k < K; k += 64) {
        float v = b2f(p[k]);
        s += v; ss += v * v;
    }
    #pragma unroll
    for (int off = 32; off > 0; off >>= 1) {
        s  += __shfl_down(s,  off, 64);
        ss += __shfl_down(ss, off, 64);
    }
    if (lane == 0) {
        float m = s / K;
        float var = ss / K - m * m;
        stats[wid * 2]     = m;
        stats[wid * 2 + 1] = rsqrtf(var + EPS);
    }
}

// ---- MFMA GEMM: 128x128 tile, BK=32, 3-buffer counted-vmcnt pipeline (T3/T4) ---
// LDS: 3 x (128x32 A + 128x32 B) = 48KB -> 3 blocks/CU. Tiles t+1,t+2 in flight;
// per tile: STAGE(t+2) | compute(t) | vmcnt(4) [waits only t+1] | one raw s_barrier.
// Bmat TRANSPOSED: [N][K] row-major. M%128==0, N%128==0, K%32==0, K/32 >= 2.
// mode 0: C = acc + bias
// mode 2: C = rstd*(acc - mean*colsum) + bias2; row stats = statsQK if col<nQK else statsX
// mode 3: qk[row][DD+col] *= sigmoid(acc + bias)  (flow+reweight fused; C = qk)
// outflag (main region, mode 0): write Cout fp32/bf16 per *outflag at outoff.
// Glob tails (A2k != null, mode 2): extra y-blocks; col [512,1024) -> A2k/stats2k/C2k,
// col [1024,1536) -> A2v/stats2v/C2v; col<512 idle. A2/stats2 padded to +128 rows.
__global__ __launch_bounds__(256)
void gemm_mfma(const bf16* __restrict__ A, int lda,
               const float* __restrict__ statsQK, const float* __restrict__ statsX,
               int nQK,
               const float* __restrict__ colsum, const float* __restrict__ bias2,
               const bf16* __restrict__ Bmat,
               const bf16* __restrict__ bias,
               bf16* __restrict__ C,
               void* __restrict__ Cout, const int* __restrict__ outflag, long long outoff,
               const bf16* __restrict__ A2k, const float* __restrict__ stats2k,
               bf16* __restrict__ C2k,
               const bf16* __restrict__ A2v, const float* __restrict__ stats2v,
               bf16* __restrict__ C2v, int M2,
               int M, int N, int K, int mode) {
    __shared__ unsigned short As[3][128 * 32];   // [buf][m][k] linear, 64B rows
    __shared__ unsigned short Bs[3][128 * 32];   // [buf][n][k] linear
    int tid = threadIdx.x;

    // general bijective XCD-chunked swizzle (m204)
    int nwgx = gridDim.x;
    int nwg = nwgx * gridDim.y;
    int orig = blockIdx.y * nwgx + blockIdx.x;
    int qq = nwg >> 3, rr = nwg & 7;
    int xcd = orig & 7, idx = orig >> 3;
    int wg = (xcd < rr ? xcd * (qq + 1) : rr * (qq + 1) + (xcd - rr) * qq) + idx;
    int gy = wg / nwgx;
    int gx = wg % nwgx;
    int bn = gx * 128;

    int nby_main = M >> 7;
    const bf16* Ap;
    const float* stp = nullptr;
    bf16* C2 = nullptr;
    int rowbase, mlim, glob, colOff = 0;
    if (gy < nby_main) {
        Ap = A; rowbase = gy * 128; mlim = M; glob = 0;
        if (mode == 2) stp = (bn >= nQK) ? statsX : statsQK;
    } else {
        if (bn < 512) return;                 // no Q projection for glob rows
        int isV = bn >= 1024;
        Ap = isV ? A2v : A2k;
        stp = isV ? stats2v : stats2k;
        C2 = isV ? C2v : C2k;
        colOff = isV ? 1024 : 512;
        rowbase = (gy - nby_main) * 128; mlim = M2; glob = 1;
    }

    int wave = tid >> 6, lane = tid & 63;
    int qm = (wave >> 1) * 64;
    int qn = (wave & 1) * 64;
    int lm = lane & 15;
    int kq = (lane >> 4) * 8;
    int sr = lane >> 2;        // 0..15: row within 16-row stage segment
    int sc = (lane & 3) * 8;   // 16B chunk within 32-elem row

    f32x4 acc[4][4];
    #pragma unroll
    for (int i = 0; i < 4; ++i)
        #pragma unroll
        for (int j = 0; j < 4; ++j)
            acc[i][j] = (f32x4){0.f, 0.f, 0.f, 0.f};

    const unsigned short* Au = (const unsigned short*)Ap;
    const unsigned short* Bu = (const unsigned short*)Bmat;

    auto STAGE = [&](int buf, int k0) {
        #pragma unroll
        for (int i = 0; i < 2; ++i) {
            int seg = wave * 2 + i;
            const unsigned short* gp =
                Au + (long long)(rowbase + seg * 16 + sr) * lda + k0 + sc;
            __builtin_amdgcn_global_load_lds(
                (const __attribute__((address_space(1))) void*)gp,
                (__attribute__((address_space(3))) void*)&As[buf][seg * 512], 16, 0, 0);
        }
        #pragma unroll
        for (int i = 0; i < 2; ++i) {
            int seg = wave * 2 + i;
            const unsigned short* gp =
                Bu + (long long)(bn + seg * 16 + sr) * K + k0 + sc;
            __builtin_amdgcn_global_load_lds(
                (const __attribute__((address_space(1))) void*)gp,
                (__attribute__((address_space(3))) void*)&Bs[buf][seg * 512], 16, 0, 0);
        }
    };
    auto COMPUTE = [&](int buf) {
        bf16x8 af[4], bfr[4];
        #pragma unroll
        for (int i = 0; i < 4; ++i)
            af[i] = *(const bf16x8*)&As[buf][(qm + i * 16 + lm) * 32 + kq];
        #pragma unroll
        for (int j = 0; j < 4; ++j)
            bfr[j] = *(const bf16x8*)&Bs[buf][(qn + j * 16 + lm) * 32 + kq];
        __builtin_amdgcn_s_setprio(1);
        #pragma unroll
        for (int i = 0; i < 4; ++i)
            #pragma unroll
            for (int j = 0; j < 4; ++j)
                acc[i][j] = __builtin_amdgcn_mfma_f32_16x16x32_bf16(
                    af[i], bfr[j], acc[i][j], 0, 0, 0);
        __builtin_amdgcn_s_setprio(0);
    };

    int nt = K >> 5;
    // prologue: stage tiles 0 and 1; wait tile 0 (leave tile 1 in flight)
    STAGE(0, 0);
    STAGE(1, 32);
    asm volatile("s_waitcnt vmcnt(4)" ::: "memory");
    __builtin_amdgcn_s_barrier();
    for (int t = 0; t < nt; ++t) {
        int cur = t % 3;
        if (t + 2 < nt) STAGE((t + 2) % 3, (t + 2) << 5);
        COMPUTE(cur);
        if (t + 2 < nt) {
            // wait tile t+1 (issued one full iteration ago); keep t+2 in flight
            asm volatile("s_waitcnt vmcnt(4)" ::: "memory");
        } else if (t + 1 < nt) {
            asm volatile("s_waitcnt vmcnt(0)" ::: "memory");
        }
        __builtin_amdgcn_s_barrier();
    }

    // ---- epilogue: C/D layout col=lane&15, row=(lane>>4)*4+reg ----
    int rq = (lane >> 4) * 4;
    float cs[4], bb[4];
    #pragma unroll
    for (int j = 0; j < 4; ++j) {
        int col = bn + qn + j * 16 + lm;
        if (mode == 2) { cs[j] = colsum[col]; bb[j] = bias2[col]; }
        else bb[j] = bias ? b2f(bias[col]) : 0.f;
    }
    int ofp = (!glob && outflag) ? *outflag : 0;
    #pragma unroll
    for (int i = 0; i < 4; ++i) {
        #pragma unroll
        for (int r = 0; r < 4; ++r) {
            int row = rowbase + qm + i * 16 + rq + r;
            if (row >= mlim) continue;
            float mean = 0.f, rstd = 0.f;
            if (mode == 2) { mean = stp[row * 2]; rstd = stp[row * 2 + 1]; }
            #pragma unroll
            for (int j = 0; j < 4; ++j) {
                int col = bn + qn + j * 16 + lm;
                float v = acc[i][j][r];
                if (mode == 2) v = rstd * (v - mean * cs[j]) + bb[j];
                else {
                    v += bb[j];
                    if (mode == 3) v = 1.f / (1.f + __expf(-v));
                }
                if (mode == 3) {
                    unsigned short* qp =
                        (unsigned short*)C + (long long)row * IC + DD + col;
                    *qp = f2u(u2f(*qp) * v);
                    continue;
                }
                if (glob) {
                    C2[(long long)row * 512 + (col - colOff)] = f2b(v);
                } else if (outflag) {
                    long long ci = (long long)row * N + col;
                    if (ofp) ((float*)Cout)[outoff + ci] = v;
                    else     ((bf16*)Cout)[outoff + ci] = f2b(v);
                } else {
                    C[(long long)row * N + col] = f2b(v);
                }
            }
        }
    }
}

// ---------------- MFMA attention (qkv fused input, stride TRI) ----------------
#define QS_STRIDE 72
#define PS_STRIDE 136
__global__ __launch_bounds__(256)
void attn_kernel(const bf16* __restrict__ qkv,
                 const bf16* __restrict__ key_glob, const bf16* __restrict__ val_glob,
                 bf16* __restrict__ attout) {
    int h = blockIdx.x & 7;
    int g = (blockIdx.x >> 3) & 63;
    int b = blockIdx.x >> 9;
    int gy = g >> 3, gx = g & 7;

    __shared__ unsigned short smem[64 * PS_STRIDE + 64 * PS_STRIDE];
    unsigned short* Qs = smem;                       // [64][QS_STRIDE]
    unsigned short* Ks = smem + 64 * QS_STRIDE;      // [128][QS_STRIDE]
    unsigned short* Ps = smem;                       // [64][PS_STRIDE]
    unsigned short* Vs = smem + 64 * PS_STRIDE;      // [64][PS_STRIDE] (d-major: [d][t])

    int tid = threadIdx.x;
    const unsigned short* QKV = (const unsigned short*)qkv;
    const unsigned short* KG = (const unsigned short*)key_glob;
    const unsigned short* VG = (const unsigned short*)val_glob;

    #pragma unroll
    for (int it = 0; it < 2; ++it) {
        int i = tid + it * 256;        // 512 units
        int t = i >> 3, dg = (i & 7) * 8;
        int ty = t >> 3, tx = t & 7;
        long long row = (long long)b * NSP + (gy * 8 + ty) * WW + gx * 8 + tx;
        *(ushort8*)&Qs[t * QS_STRIDE + dg] =
            *(const ushort8*)&QKV[row * TRI + h * 64 + dg];
    }
    #pragma unroll
    for (int it = 0; it < 4; ++it) {
        int i = tid + it * 256;        // 1024 units
        int t = i >> 3, dg = (i & 7) * 8;
        ushort8 kv;
        if (t < 64) {
            int ty = t >> 3, tx = t & 7;
            long long row = (long long)b * NSP + (gy * 8 + ty) * WW + gx * 8 + tx;
            kv = *(const ushort8*)&QKV[row * TRI + 512 + h * 64 + dg];
        } else {
            long long srow = (long long)b * NM + (t - 64);
            kv = *(const ushort8*)&KG[srow * DD + h * 64 + dg];
        }
        *(ushort8*)&Ks[t * QS_STRIDE + dg] = kv;
    }
    __syncthreads();

    int wave = tid >> 6, lane = tid & 63;
    int m0 = wave * 16;
    int lm = lane & 15;
    int quad = lane >> 4;            // 0..3

    f32x4 sacc[8];
    #pragma unroll
    for (int j = 0; j < 8; ++j) sacc[j] = (f32x4){0.f, 0.f, 0.f, 0.f};
    #pragma unroll
    for (int ks = 0; ks < 2; ++ks) {
        int kq = quad * 8 + ks * 32;
        bf16x8 af = *(const bf16x8*)&Qs[(m0 + lm) * QS_STRIDE + kq];
        #pragma unroll
        for (int j = 0; j < 8; ++j) {
            bf16x8 bfr = *(const bf16x8*)&Ks[(j * 16 + lm) * QS_STRIDE + kq];
            sacc[j] = __builtin_amdgcn_mfma_f32_16x16x32_bf16(af, bfr, sacc[j], 0, 0, 0);
        }
    }
    float pinv[4];
    #pragma unroll
    for (int r = 0; r < 4; ++r) {
        float mx = -1e30f;
        #pragma unroll
        for (int j = 0; j < 8; ++j) {
            sacc[j][r] *= 0.125f;
            mx = fmaxf(mx, sacc[j][r]);
        }
        mx = fmaxf(mx, __shfl_xor(mx, 1, 64));
        mx = fmaxf(mx, __shfl_xor(mx, 2, 64));
        mx = fmaxf(mx, __shfl_xor(mx, 4, 64));
        mx = fmaxf(mx, __shfl_xor(mx, 8, 64));
        float l = 0.f;
        #pragma unroll
        for (int j = 0; j < 8; ++j) {
            float p = __expf(sacc[j][r] - mx);
            sacc[j][r] = p;
            l += p;
        }
        l += __shfl_xor(l, 1, 64);
        l += __shfl_xor(l, 2, 64);
        l += __shfl_xor(l, 4, 64);
        l += __shfl_xor(l, 8, 64);
        pinv[r] = 1.f / l;
    }
    __syncthreads();   // all waves done reading Qs/Ks

    #pragma unroll
    for (int r = 0; r < 4; ++r) {
        int qrow = m0 + quad * 4 + r;
        #pragma unroll
        for (int j = 0; j < 8; ++j)
            Ps[qrow * PS_STRIDE + j * 16 + lm] = f2u(sacc[j][r] * pinv[r]);
    }
    #pragma unroll
    for (int it = 0; it < 4; ++it) {
        int i = tid + it * 256;        // 1024 units: t=128, dg=8
        int t = i & 127, dg = (i >> 7) * 8;
        ushort8 v;
        if (t < 64) {
            int ty = t >> 3, tx = t & 7;
            long long row = (long long)b * NSP + (gy * 8 + ty) * WW + gx * 8 + tx;
            v = *(const ushort8*)&QKV[row * TRI + 1024 + h * 64 + dg];
        } else {
            long long srow = (long long)b * NM + (t - 64);
            v = *(const ushort8*)&VG[srow * DD + h * 64 + dg];
        }
        #pragma unroll
        for (int e = 0; e < 8; ++e) Vs[(dg + e) * PS_STRIDE + t] = v[e];
    }
    __syncthreads();

    f32x4 oacc[4];
    #pragma unroll
    for (int j = 0; j < 4; ++j) oacc[j] = (f32x4){0.f, 0.f, 0.f, 0.f};
    #pragma unroll
    for (int ks = 0; ks < 4; ++ks) {
        int kq = quad * 8 + ks * 32;
        bf16x8 af = *(const bf16x8*)&Ps[(m0 + lm) * PS_STRIDE + kq];
        #pragma unroll
        for (int j = 0; j < 4; ++j) {
            bf16x8 bfr = *(const bf16x8*)&Vs[(j * 16 + lm) * PS_STRIDE + kq];
            oacc[j] = __builtin_amdgcn_mfma_f32_16x16x32_bf16(af, bfr, oacc[j], 0, 0, 0);
        }
    }
    #pragma unroll
    for (int r = 0; r < 4; ++r) {
        int qrow = m0 + quad * 4 + r;
        int ty = qrow >> 3, tx = qrow & 7;
        long long orow = (long long)b * NSP + (gy * 8 + ty) * WW + gx * 8 + tx;
        unsigned short* op = (unsigned short*)attout + orow * DD + h * 64;
        #pragma unroll
        for (int j = 0; j < 4; ++j)
            op[j * 16 + lm] = f2u(oacc[j][r]);
    }
}

static inline size_t alg(size_t b) { return (b + 255) & ~(size_t)255; }

extern "C" void kernel_launch(void* const* d_in, const int* in_sizes, int n_in,
                              void* d_out, int out_size, void* d_ws, size_t ws_size,
                              hipStream_t stream) {
    int s = (n_in > 2 && in_sizes[2] == 1) ? 0 : -1;

    const void* xv = d_in[0];
    const void* fv = d_in[1];
    const void* wsrc[NW];
    for (int i = 0; i < NW; ++i) wsrc[i] = d_in[3 + s + i];
    (void)out_size;

    const int wcnt[NW] = {327680, 512, 327680, 512, 262144, 512, 262144, 512,
                          40960, 640, 32768, 512, 640, 640, 640, 640, 512, 512,
                          81920, 128};
    WTab tab;
    int pre = 0;
    for (int i = 0; i < NW; ++i) {
        tab.src[i] = wsrc[i];
        tab.pre[i] = pre;
        pre += wcnt[i];
    }
    tab.pre[NW] = pre;
    const int wtotal = pre;

    char* ws = (char*)d_ws;
    size_t head = 0;
    int* flag = (int*)(ws + head); head += 256;
    bf16* wc = (bf16*)(ws + head); head += alg((size_t)wtotal * 2);
    // transposed weights: qkvW [1536][640] | WoT [512][512] | rwT [128][640]
    //                     | wkT [64][640] | wvT [64][512]
    const int off_qkvW = 0;
    const int off_WoT  = TRI * IC;                 // 983040
    const int off_rwT  = off_WoT + DD * DD;        // 1245184
    const int off_wkT  = off_rwT + CF * IC;        // 1327104
    const int off_wvT  = off_wkT + 64 * IC;        // 1368064
    const int wtpre    = off_wvT + 64 * DD;        // 1400832
    bf16* wt = (bf16*)(ws + head); head += alg((size_t)wtpre * 2);
    float* foldv = (float*)(ws + head); head += alg(2 * TRI * sizeof(float));
    float* cs_qkv = foldv;
    float* b2_qkv = foldv + TRI;

    const bf16* bq     = wc + tab.pre[1];
    const bf16* bk     = wc + tab.pre[3];
    const bf16* bv     = wc + tab.pre[5];
    const bf16* bo     = wc + tab.pre[7];
    const bf16* convKb = wc + tab.pre[9];
    const bf16* convVb = wc + tab.pre[11];
    const bf16* qn_g   = wc + tab.pre[12];
    const bf16* qn_b   = wc + tab.pre[13];
    const bf16* kn_g   = wc + tab.pre[14];
    const bf16* kn_b   = wc + tab.pre[15];
    const bf16* vn_g   = wc + tab.pre[16];
    const bf16* vn_b   = wc + tab.pre[17];
    const bf16* rw_b   = wc + tab.pre[19];
    bf16* qkvW = wt + off_qkvW;
    bf16* WoT  = wt + off_WoT;
    bf16* rwT  = wt + off_rwT;
    bf16* wkT  = wt + off_wkT;
    bf16* wvT  = wt + off_wvT;

    size_t avail = ws_size > head ? ws_size - head : 0;
    auto need = [&](int bc) -> size_t {
        size_t rows = (size_t)bc * NSP;
        size_t gm = (size_t)bc * NM, gmp = gm + 128;
        return alg(rows * IC * 2) + alg(rows * TRI * 2)
             + 2 * alg(gmp * IC * 2) + 2 * alg(gm * DD * 2)
             + 2 * alg(rows * 8) + 2 * alg(gmp * 8);
    };
    int nb = BT;
    while (nb > 1 && need(nb) > avail) nb--;

    detect_dtype<<<1, 256, 0, stream>>>(xv, flag);
    convert_weights<<<(wtotal + 255) / 256, 256, 0, stream>>>(tab, flag, wc, wtotal);
    {
        TT tt;
        const int srcsel[NSEG] = {0, 2, 4, 6, 18, 8, 10};
        const int Rr[NSEG]     = {IC, IC, DD, DD, IC, IC, DD};
        const int Cc[NSEG]     = {DD, DD, DD, DD, CF, 64, 64};
        const int dof[NSEG]    = {0, DD * IC, 2 * DD * IC, off_WoT, off_rwT,
                                  off_wkT, off_wvT};
        const int dstr[NSEG]   = {IC, IC, IC, DD, IC, IC, DD};
        int tp = 0;
        for (int i = 0; i < NSEG; ++i) {
            tt.srcoff[i] = tab.pre[srcsel[i]];
            tt.dstoff[i] = dof[i];
            tt.R[i] = Rr[i];
            tt.C[i] = Cc[i];
            tt.dstride[i] = dstr[i];
            tt.tpre[i] = tp;
            tp += (Rr[i] / 32) * (Cc[i] / 32);
        }
        tt.tpre[NSEG] = tp;
        transpose_weights<<<tp, 256, 0, stream>>>(wc, wt, tt);
    }
    // fold LN into qkvW rows; V region zero-padded in K to 640
    fold_ln_weights<<<DD, 256, 0, stream>>>(qkvW,              IC, qn_g, qn_b, bq,
                                            cs_qkv,       b2_qkv,       IC, IC);
    fold_ln_weights<<<DD, 256, 0, stream>>>(qkvW + DD * IC,    IC, kn_g, kn_b, bk,
                                            cs_qkv + 512, b2_qkv + 512, IC, IC);
    fold_ln_weights<<<DD, 256, 0, stream>>>(qkvW + 2 * DD * IC, IC, vn_g, vn_b, bv,
                                            cs_qkv + 1024, b2_qkv + 1024, DD, IC);

    for (int b0 = 0; b0 < BT; b0 += nb) {
        int bc = BT - b0 < nb ? BT - b0 : nb;
        int rows = bc * NSP;
        int gm = bc * NM;           // glob rows this chunk
        int gyg = (gm + 127) / 128; // extra y-blocks for glob tail

        size_t off = head;
        auto alloc = [&](size_t bytes) -> void* {
            void* p = ws + off; off += alg(bytes); return p;
        };
        size_t gmp = (size_t)gm + 128;  // padded for OOB staging reads
        bf16* qk        = (bf16*)alloc((size_t)rows * IC * 2);
        bf16* qkv       = (bf16*)alloc((size_t)rows * TRI * 2);
        bf16* kg        = (bf16*)alloc(gmp * IC * 2);
        bf16* vg        = (bf16*)alloc(gmp * IC * 2);   // stride IC, cols 512.. zeroed
        bf16* key_glob  = (bf16*)alloc((size_t)gm * DD * 2);
        bf16* val_glob  = (bf16*)alloc((size_t)gm * DD * 2);
        float* stats_qk = (float*)alloc((size_t)rows * 8);
        float* stats_x  = (float*)alloc((size_t)rows * 8);
        float* stats_kg = (float*)alloc(gmp * 8);
        float* stats_vg = (float*)alloc(gmp * 8);
        bf16* attout    = qk;        // alias: qk dead after fused QKV GEMM

        // 1. assemble qk = [x | f]
        {
            long long total = (long long)rows * 80;
            int blocks = (int)((total + 255) / 256);
            assemble_qk_v<<<blocks, 256, 0, stream>>>(
                xv, fv, flag, qk, rows,
                (long long)b0 * NSP * DD, (long long)b0 * NSP * CF);
        }
        // 2. flow gemm + reweight fused (mode 3): qk.f *= sigmoid(qk @ rw_W + rw_b)
        gemm_mfma<<<dim3(CF / 128, rows / 128), 256, 0, stream>>>(
            qk, IC, nullptr, nullptr, 0, nullptr, nullptr, rwT, rw_b, qk,
            nullptr, nullptr, 0,
            nullptr, nullptr, nullptr, nullptr, nullptr, nullptr, 0,
            rows, CF, IC, 3);
        // 3. vectorized depthwise convs (K + V in one pass over qk)
        dwconv_fast<<<bc * NM * 10, 256, 0, stream>>>(
            qk, wkT, convKb, wvT, convVb, kg, vg);
        // 4. LN stats
        stats_fused<<<rows / 4, 256, 0, stream>>>(qk, stats_qk, stats_x, rows);
        stats_kernel<<<(gm * 64 + 255) / 256, 256, 0, stream>>>(kg, IC, stats_kg, gm, IC);
        stats_kernel<<<(gm * 64 + 255) / 256, 256, 0, stream>>>(vg, IC, stats_vg, gm, DD);
        // 5. fused QKV projection (N=1536) + glob tails
        gemm_mfma<<<dim3(TRI / 128, rows / 128 + gyg), 256, 0, stream>>>(
            qk, IC, stats_qk, stats_x, 1024, cs_qkv, b2_qkv, qkvW, nullptr, qkv,
            nullptr, nullptr, 0,
            kg, stats_kg, key_glob, vg, stats_vg, val_glob, gm,
            rows, TRI, IC, 2);
        // 6. attention
        attn_kernel<<<bc * NG * 8, 256, 0, stream>>>(qkv, key_glob, val_glob, attout);
        // 7. output projection -> d_out directly with dtype dispatch
        gemm_mfma<<<dim3(DD / 128, rows / 128), 256, 0, stream>>>(
            attout, DD, nullptr, nullptr, 0, nullptr, nullptr, WoT, bo, nullptr,
            d_out, flag, (long long)b0 * NSP * DD,
            nullptr, nullptr, nullptr, nullptr, nullptr, nullptr, 0,
            rows, DD, DD, 0);
    }
}